// Round 6
// baseline (682.054 us; speedup 1.0000x reference)
//
#include <hip/hip_runtime.h>
#include <hip/hip_fp16.h>

// LinearCDE chunked parallel scan, MFMA edition, adaptive workspace.
//   y_t = y_{t-1} + A_t y_{t-1} + b_t;  A_t = reshape(inp_t @ Wa^T, [H,H])
// R21: latency-depth attack, bit-identical math. R20's counters finally
// isolated the bottleneck: k_emit 56us/slice with MfmaUtil 0, VALU 7.7%,
// HBM 1.76 TB/s of 6.4 achievable, occupancy grid-capped at 2 blocks/CU.
// VALU work is ~4us -> emit is in-flight-bytes-starved (Little's law:
// 2-deep x 8KB/wave in flight => ~2 TB/s ceiling). Fix: 3-deep rotating
// prefetch (arA/B/C) + hoist steps 0-2 and prefix-j0 loads to kernel entry
// so their latency hides under the ~9 serial scan steps. Same treatment
// for chunkmap's LOADA (hoisted above the A0 staging). launch_bounds
// (256,2) caps VGPR at 256 -- 2 blocks/CU preserved (grid gives no more).
// Dispatch structure unchanged (R16/17/19/20: boundary theory exhausted).
// History: R16 grid.sync=671, R17 acq_rel=844, R18=607, R19 smap=783,
// R20 emit-scan=615 (chainsuper removal neutral; kept for the counters).

typedef _Float16 h8 __attribute__((ext_vector_type(8)));
typedef float v4f __attribute__((ext_vector_type(4)));
typedef unsigned int uint;

constexpr int B_ = 8, S_ = 2048, D_ = 64, H_ = 128;
constexpr int T_ = S_ - 1;              // 2047
constexpr int KD = D_ + 1;              // 65
constexpr float DTC = 1.0f / 2047.0f;
constexpr int L_ = 8;                   // chunk length
constexpr int LSH = 3;                  // log2(L_)
constexpr int NC = 256;                 // chunks per batch (last has 7 steps)

// ---------------- k_prep: merged prep ----------------
__global__ __launch_bounds__(256) void k_prep(const float* __restrict__ Wa,
                                              _Float16* __restrict__ Wa16B,
                                              float* __restrict__ Wa0,
                                              const float* __restrict__ X,
                                              _Float16* __restrict__ Xs16,
                                              const float* __restrict__ Wb,
                                              float* __restrict__ Bs,
                                              const float* __restrict__ Wi,
                                              const float* __restrict__ bi,
                                              float* __restrict__ out,
                                              float* __restrict__ yb) {
  __shared__ float wb_s[H_ * KD];
  __shared__ float xs[16][D_ + 4];
  int bx = blockIdx.x, tid = threadIdx.x;
  if (bx < 4096) {
    int idx = bx * 256 + tid;             // 16384*64 exact
    int r = idx >> 6, kk = idx & 63;
    int rt = r >> 4, n = r & 15;
    int kb = kk >> 5, q = (kk >> 3) & 3, jj = kk & 7;
    float v = Wa[(size_t)r * KD + 1 + kk];
    Wa16B[((((size_t)rt * 2 + kb) * 4 + q) * 16 + n) * 8 + jj] = (_Float16)v;
    if (kk == 0) Wa0[r] = Wa[(size_t)r * KD];
  } else if (bx < 8190) {
    int idx = (bx - 4096) * 256 + tid;    // 4094*256 >= B*T*64 exact
    if (idx < B_ * T_ * 64) {
      int bt = idx >> 6, d = idx & 63;
      int b = bt / T_, s = bt - b * T_;
      Xs16[(size_t)bt * 64 + d] = (_Float16)(X[((size_t)b * S_ + s + 1) * D_ + d] * DTC);
    }
  } else if (bx < 9214) {
    int bt0 = (bx - 8190) * 16;
    for (int i2 = tid; i2 < H_ * KD; i2 += 256) wb_s[i2] = Wb[i2];
    for (int i2 = tid; i2 < 16 * D_; i2 += 256) {
      int sl = i2 >> 6, d = i2 & 63;
      int btg = bt0 + sl;
      float v = 0.f;
      if (btg < B_ * T_) {
        int b = btg / T_, s = btg - b * T_;
        v = X[((size_t)b * S_ + s + 1) * D_ + d] * DTC;
      }
      xs[sl][d] = v;
    }
    __syncthreads();
    int h = tid & 127, sh = tid >> 7;
    const float* wrow = &wb_s[h * KD];
    for (int u = 0; u < 8; u++) {
      int sl = sh * 8 + u;
      int btg = bt0 + sl;
      if (btg >= B_ * T_) break;
      float acc = wrow[0] * DTC;
#pragma unroll 8
      for (int d = 0; d < D_; d++) acc += xs[sl][d] * wrow[1 + d];
      Bs[(size_t)btg * H_ + h] = acc;
    }
  } else {
    int b = bx - 9214;
    if (tid < D_) xs[0][tid] = X[(size_t)b * S_ * D_ + tid];
    __syncthreads();
    if (tid < H_) {
      float acc = bi[tid];
      const float* wr = Wi + tid * D_;
#pragma unroll 8
      for (int d = 0; d < D_; d++) acc += xs[0][d] * wr[d];
      out[(size_t)b * S_ * H_ + tid] = acc;
      yb[(size_t)(b * NC + 0) * H_ + tid] = acc;
    }
  }
}

// ---------------- k_amat v2: 32t x 512el tiles, contiguous 1KB writes -----
__global__ __launch_bounds__(256) void k_amat(const _Float16* __restrict__ Xs16,
                                              const _Float16* __restrict__ Wa16B,
                                              const float* __restrict__ Wa0,
                                              _Float16* __restrict__ A_sl,
                                              int c0, int scShift) {
  __shared__ _Float16 sb[32 * 528];    // 33.8 KB
  int tid = threadIdx.x;
  int w = tid >> 6, lane = tid & 63;
  int n = lane & 15, q = lane >> 4;
  int rowbase = blockIdx.x * 32;
  int SCm = ((1 << scShift) << LSH) - 1;

  h8 af[2][2];
#pragma unroll
  for (int mi = 0; mi < 2; mi++) {
    int sidx = rowbase + mi * 16 + n;
    int b = sidx >> (scShift + LSH);
    int rem = sidx & SCm;
    int cc = rem >> LSH, l = rem & (L_ - 1);
    int s = (c0 + cc) * L_ + l;
    if (s >= T_) s = T_ - 1;
    size_t btg = (size_t)b * T_ + s;
#pragma unroll
    for (int kb = 0; kb < 2; kb++)
      af[mi][kb] = *(const h8*)(Xs16 + btg * 64 + kb * 32 + q * 8);
  }

  v4f acc[2][8];
#pragma unroll
  for (int nj = 0; nj < 8; nj++) {
    int ct_g = blockIdx.y * 32 + w * 8 + nj;
    float binit = DTC * Wa0[ct_g * 16 + n];
    h8 bf0 = *(const h8*)(Wa16B + ((((size_t)ct_g * 2 + 0) * 4 + q) * 16 + n) * 8);
    h8 bf1 = *(const h8*)(Wa16B + ((((size_t)ct_g * 2 + 1) * 4 + q) * 16 + n) * 8);
#pragma unroll
    for (int mi = 0; mi < 2; mi++) {
      v4f a;
      a[0] = binit; a[1] = binit; a[2] = binit; a[3] = binit;
      a = __builtin_amdgcn_mfma_f32_16x16x32_f16(af[mi][0], bf0, a, 0, 0, 0);
      a = __builtin_amdgcn_mfma_f32_16x16x32_f16(af[mi][1], bf1, a, 0, 0, 0);
      acc[mi][nj] = a;
    }
  }
#pragma unroll
  for (int mi = 0; mi < 2; mi++)
#pragma unroll
    for (int nj = 0; nj < 8; nj++)
#pragma unroll
      for (int reg = 0; reg < 4; reg++)
        sb[(mi * 16 + q * 4 + reg) * 528 + w * 128 + ((nj * 16 + n) ^ (q * 16))] =
            (_Float16)acc[mi][nj][reg];
  __syncthreads();
#pragma unroll
  for (int it = 0; it < 8; it++) {
    int idx = tid + it * 256;
    int t = idx >> 6, u4 = idx & 63;
    int qt = (t >> 2) & 3;
    uint4 val = *(const uint4*)&sb[t * 528 + ((u4 * 8) ^ (qt * 16))];
    *(uint4*)(A_sl + (size_t)(rowbase + t) * 16384 + blockIdx.y * 512 + u4 * 8) = val;
  }
}

// ---------------- chunkmap body: chunk map via 7 serial compositions ------
// R21: 3-deep rotating LOADA (afA/B/C), hoisted above the A0 staging so
// step-1..3 loads are in flight during staging + barrier. Math verbatim.
__device__ __forceinline__ void chunkmap_body(const _Float16* __restrict__ A_sl,
                                              const float* __restrict__ Bs,
                                              _Float16* __restrict__ Mr,
                                              float* __restrict__ vch,
                                              int c0, int scShift, int chunk, int tid,
                                              _Float16* Dt, float* v32) {
  int w = tid >> 6, lane = tid & 63;
  int n = lane & 15, q = lane >> 4;
  int SC = 1 << scShift;
  int b = chunk >> scShift;
  int cc = chunk & (SC - 1);
  int c = c0 + cc;
  int sbase = c * L_;
  int nsteps = min(L_, T_ - sbase);     // 7 or 8 for this problem
  const _Float16* Abase = A_sl + (size_t)chunk * L_ * 16384;
  size_t btb = (size_t)b * T_ + sbase;

  h8 afA[2][4], afB[2][4], afC[2][4];   // 3-deep named buffers

#define LOADA(dst, l)                                                                \
  {                                                                                  \
    const _Float16* Ag = Abase + (size_t)(l) * 16384;                                \
    _Pragma("unroll")                                                                \
    for (int mi = 0; mi < 2; mi++)                                                   \
      _Pragma("unroll")                                                              \
      for (int kb = 0; kb < 4; kb++)                                                 \
        dst[mi][kb] = *(const h8*)(Ag + ((2 * w + mi) * 16 + n) * 128 + kb * 32 + q * 8); \
  }

  // hoisted: steps 1..3 (always exist: nsteps >= 7) overlap the staging
  LOADA(afA, 1);
  LOADA(afB, 2);
  LOADA(afC, 3);

  // stage A0^T (conflict-free R10 mapping)
#pragma unroll
  for (int it = 0; it < 8; it++) {
    int idx = tid + it * 256;
    int rowl = idx & 127, c8 = (idx >> 7) * 8;
    uint4 pk = *(const uint4*)(Abase + rowl * 128 + c8);
    const _Float16* hp = (const _Float16*)&pk;
#pragma unroll
    for (int cx = 0; cx < 8; cx++) Dt[(c8 + cx) * 136 + rowl] = hp[cx];
  }
  if (tid < 128) v32[tid] = Bs[btb * 128 + tid];
  h8 idE, idO;
#pragma unroll
  for (int jj = 0; jj < 8; jj++) {
    idE[jj] = (_Float16)((q * 8 + jj == n) ? 1.f : 0.f);
    idO[jj] = (_Float16)((q * 8 + jj == 16 + n) ? 1.f : 0.f);
  }
  __syncthreads();

  v4f acc[2][8];
#pragma unroll
  for (int mi = 0; mi < 2; mi++) {
    int row0 = (2 * w + mi) * 16 + q * 4;
#pragma unroll
    for (int nj = 0; nj < 8; nj++) {
      int col = nj * 16 + n;
      union { uint2 u; _Float16 h[4]; } m2;
      m2.u = *(const uint2*)&Dt[col * 136 + row0];
#pragma unroll
      for (int reg = 0; reg < 4; reg++) acc[mi][nj][reg] = (float)m2.h[reg];
    }
  }

  int r0 = 2 * w * 16 + n, r1 = r0 + 16;

#define STEPQ(af, l)                                                                 \
  {                                                                                  \
    _Pragma("unroll")                                                                \
    for (int nj = 0; nj < 8; nj++) {                                                 \
      h8 bfr[4];                                                                     \
      _Pragma("unroll")                                                              \
      for (int kb = 0; kb < 4; kb++)                                                 \
        bfr[kb] = *(const h8*)&Dt[(nj * 16 + n) * 136 + kb * 32 + q * 8];            \
      _Pragma("unroll")                                                              \
      for (int mi = 0; mi < 2; mi++) {                                               \
        _Pragma("unroll")                                                            \
        for (int kb = 0; kb < 4; kb++)                                               \
          acc[mi][nj] = __builtin_amdgcn_mfma_f32_16x16x32_f16(af[mi][kb], bfr[kb], acc[mi][nj], 0, 0, 0); \
        acc[mi][nj] = __builtin_amdgcn_mfma_f32_16x16x32_f16(                        \
            af[mi][nj >> 1], (nj & 1) ? idO : idE, acc[mi][nj], 0, 0, 0);            \
      }                                                                              \
    }                                                                                \
    float dv0 = 0.f, dv1 = 0.f;                                                      \
    _Pragma("unroll")                                                                \
    for (int kb = 0; kb < 4; kb++) {                                                 \
      float4 p0 = *(const float4*)&v32[kb * 32 + q * 8];                             \
      float4 p1 = *(const float4*)&v32[kb * 32 + q * 8 + 4];                         \
      float vk[8] = {p0.x, p0.y, p0.z, p0.w, p1.x, p1.y, p1.z, p1.w};                \
      _Pragma("unroll")                                                              \
      for (int jj = 0; jj < 8; jj++) {                                               \
        dv0 += (float)af[0][kb][jj] * vk[jj];                                        \
        dv1 += (float)af[1][kb][jj] * vk[jj];                                        \
      }                                                                              \
    }                                                                                \
    dv0 += __shfl_xor(dv0, 16); dv0 += __shfl_xor(dv0, 32);                          \
    dv1 += __shfl_xor(dv1, 16); dv1 += __shfl_xor(dv1, 32);                          \
    float vold0 = v32[r0], vold1 = v32[r1];                                          \
    float bs0 = 0.f, bs1 = 0.f;                                                      \
    if (q == 0) {                                                                    \
      bs0 = Bs[(btb + (l)) * 128 + r0];                                              \
      bs1 = Bs[(btb + (l)) * 128 + r1];                                              \
    }                                                                                \
    __syncthreads();                                                                 \
    _Pragma("unroll")                                                                \
    for (int mi = 0; mi < 2; mi++) {                                                 \
      int row0 = (2 * w + mi) * 16 + q * 4;                                          \
      _Pragma("unroll")                                                              \
      for (int nj = 0; nj < 8; nj++) {                                               \
        int col = nj * 16 + n;                                                       \
        union { _Float16 h[4]; uint2 u; } pk;                                        \
        _Pragma("unroll")                                                            \
        for (int reg = 0; reg < 4; reg++) pk.h[reg] = (_Float16)acc[mi][nj][reg];    \
        *(uint2*)&Dt[col * 136 + row0] = pk.u;                                       \
      }                                                                              \
    }                                                                                \
    if (q == 0) {                                                                    \
      v32[r0] = vold0 + dv0 + bs0;                                                   \
      v32[r1] = vold1 + dv1 + bs1;                                                   \
    }                                                                                \
    __syncthreads();                                                                 \
  }

  // straight-line 3-deep schedule (steps 1..nsteps-1; nsteps in {7,8})
  STEPQ(afA, 1); LOADA(afA, 4);
  STEPQ(afB, 2); LOADA(afB, 5);
  STEPQ(afC, 3); LOADA(afC, 6);
  STEPQ(afA, 4); if (7 < nsteps) LOADA(afA, 7);
  STEPQ(afB, 5);
  STEPQ(afC, 6);
  if (7 < nsteps) STEPQ(afA, 7);
#undef LOADA
#undef STEPQ

#pragma unroll
  for (int mi = 0; mi < 2; mi++) {
    int row0 = (2 * w + mi) * 16 + q * 4;
#pragma unroll
    for (int nj = 0; nj < 8; nj++) {
      int col = nj * 16 + n;
#pragma unroll
      for (int reg = 0; reg < 4; reg++)
        Dt[(row0 + reg) * 136 + col] = (_Float16)acc[mi][nj][reg];
    }
  }
  __syncthreads();
  _Float16* og = Mr + (size_t)chunk * 16384;
#pragma unroll
  for (int it = 0; it < 8; it++) {
    int idx = tid + it * 256;
    int rowl = idx >> 4, ch = idx & 15;
    uint4 val = *(const uint4*)&Dt[rowl * 136 + ch * 8];
    *(uint4*)(og + rowl * 128 + ch * 8) = val;
  }
  if (tid < 128) vch[(size_t)chunk * 128 + tid] = v32[tid];
}

// ---------------- comp4 body: compose 4 consecutive delta maps ------------
__device__ __forceinline__ void comp4_body(const _Float16* __restrict__ in_map,
                                           const float* __restrict__ in_v,
                                           _Float16* __restrict__ out_map,
                                           float* __restrict__ out_v,
                                           int outIdx, int tid,
                                           _Float16* Dt, float* v32) {
  int w = tid >> 6, lane = tid & 63;
  int n = lane & 15, q = lane >> 4;
  size_t nbase = (size_t)outIdx * 4;

  const _Float16* P0 = in_map + nbase * 16384;
#pragma unroll
  for (int it = 0; it < 8; it++) {
    int idx = tid + it * 256;
    int rowl = idx & 127, c8 = (idx >> 7) * 8;
    uint4 pk = *(const uint4*)(P0 + rowl * 128 + c8);
    const _Float16* hp = (const _Float16*)&pk;
#pragma unroll
    for (int cx = 0; cx < 8; cx++) Dt[(c8 + cx) * 136 + rowl] = hp[cx];
  }
  if (tid < 128) v32[tid] = in_v[nbase * 128 + tid];
  h8 idE, idO;
#pragma unroll
  for (int jj = 0; jj < 8; jj++) {
    idE[jj] = (_Float16)((q * 8 + jj == n) ? 1.f : 0.f);
    idO[jj] = (_Float16)((q * 8 + jj == 16 + n) ? 1.f : 0.f);
  }
  __syncthreads();

  v4f acc[2][8];
#pragma unroll
  for (int mi = 0; mi < 2; mi++) {
    int row0 = (2 * w + mi) * 16 + q * 4;
#pragma unroll
    for (int nj = 0; nj < 8; nj++) {
      int col = nj * 16 + n;
      union { uint2 u; _Float16 h[4]; } m2;
      m2.u = *(const uint2*)&Dt[col * 136 + row0];
#pragma unroll
      for (int reg = 0; reg < 4; reg++) acc[mi][nj][reg] = (float)m2.h[reg];
    }
  }

  int r0 = 2 * w * 16 + n, r1 = r0 + 16;
  for (int j = 1; j < 4; j++) {
    const _Float16* Pj = in_map + (nbase + j) * 16384;
    h8 af[2][4];
#pragma unroll
    for (int mi = 0; mi < 2; mi++)
#pragma unroll
      for (int kb = 0; kb < 4; kb++)
        af[mi][kb] = *(const h8*)(Pj + ((2 * w + mi) * 16 + n) * 128 + kb * 32 + q * 8);
#pragma unroll
    for (int nj = 0; nj < 8; nj++) {
      h8 bfr[4];
#pragma unroll
      for (int kb = 0; kb < 4; kb++)
        bfr[kb] = *(const h8*)&Dt[(nj * 16 + n) * 136 + kb * 32 + q * 8];
#pragma unroll
      for (int mi = 0; mi < 2; mi++) {
#pragma unroll
        for (int kb = 0; kb < 4; kb++)
          acc[mi][nj] = __builtin_amdgcn_mfma_f32_16x16x32_f16(af[mi][kb], bfr[kb], acc[mi][nj], 0, 0, 0);
        acc[mi][nj] = __builtin_amdgcn_mfma_f32_16x16x32_f16(
            af[mi][nj >> 1], (nj & 1) ? idO : idE, acc[mi][nj], 0, 0, 0);
      }
    }
    float dv0 = 0.f, dv1 = 0.f;
#pragma unroll
    for (int kb = 0; kb < 4; kb++) {
      float4 p0 = *(const float4*)&v32[kb * 32 + q * 8];
      float4 p1 = *(const float4*)&v32[kb * 32 + q * 8 + 4];
      float vk[8] = {p0.x, p0.y, p0.z, p0.w, p1.x, p1.y, p1.z, p1.w};
#pragma unroll
      for (int jj = 0; jj < 8; jj++) {
        dv0 += (float)af[0][kb][jj] * vk[jj];
        dv1 += (float)af[1][kb][jj] * vk[jj];
      }
    }
    dv0 += __shfl_xor(dv0, 16); dv0 += __shfl_xor(dv0, 32);
    dv1 += __shfl_xor(dv1, 16); dv1 += __shfl_xor(dv1, 32);
    float vold0 = v32[r0], vold1 = v32[r1];
    float vj0 = 0.f, vj1 = 0.f;
    if (q == 0) {
      vj0 = in_v[(nbase + j) * 128 + r0];
      vj1 = in_v[(nbase + j) * 128 + r1];
    }
    __syncthreads();
#pragma unroll
    for (int mi = 0; mi < 2; mi++) {
      int row0 = (2 * w + mi) * 16 + q * 4;
#pragma unroll
      for (int nj = 0; nj < 8; nj++) {
        int col = nj * 16 + n;
        union { _Float16 h[4]; uint2 u; } pk;
#pragma unroll
        for (int reg = 0; reg < 4; reg++) pk.h[reg] = (_Float16)acc[mi][nj][reg];
        *(uint2*)&Dt[col * 136 + row0] = pk.u;
      }
    }
    if (q == 0) {
      v32[r0] = vold0 + dv0 + vj0;
      v32[r1] = vold1 + dv1 + vj1;
    }
    __syncthreads();
  }
#pragma unroll
  for (int mi = 0; mi < 2; mi++) {
    int row0 = (2 * w + mi) * 16 + q * 4;
#pragma unroll
    for (int nj = 0; nj < 8; nj++) {
      int col = nj * 16 + n;
#pragma unroll
      for (int reg = 0; reg < 4; reg++)
        Dt[(row0 + reg) * 136 + col] = (_Float16)acc[mi][nj][reg];
    }
  }
  __syncthreads();
  _Float16* og = out_map + (size_t)outIdx * 16384;
#pragma unroll
  for (int it = 0; it < 8; it++) {
    int idx = tid + it * 256;
    int rowl = idx >> 4, ch = idx & 15;
    uint4 val = *(const uint4*)&Dt[rowl * 136 + ch * 8];
    *(uint4*)(og + rowl * 128 + ch * 8) = val;
  }
  if (tid < 128) out_v[(size_t)outIdx * 128 + tid] = v32[tid];
}

// ---------------- standalone stage kernels ----------------
__global__ __launch_bounds__(256, 2) void k_chunkmap(const _Float16* __restrict__ A_sl,
                                                     const float* __restrict__ Bs,
                                                     _Float16* __restrict__ Mr,
                                                     float* __restrict__ vch,
                                                     int c0, int scShift) {
  __shared__ _Float16 Dt[128 * 136];
  __shared__ float v32[128];
  chunkmap_body(A_sl, Bs, Mr, vch, c0, scShift, blockIdx.x, threadIdx.x, Dt, v32);
}

__global__ __launch_bounds__(256) void k_comp4(const _Float16* __restrict__ in_map,
                                               const float* __restrict__ in_v,
                                               _Float16* __restrict__ out_map,
                                               float* __restrict__ out_v) {
  __shared__ _Float16 Dt[128 * 136];
  __shared__ float v32[128];
  comp4_body(in_map, in_v, out_map, out_v, blockIdx.x, threadIdx.x, Dt, v32);
}

// ---------------- k_emit: supermap scan + prefix + 8 chunk steps ----------
// R21: chunk-step loads 0..2 + prefix-j0 hoisted to entry (latency hides
// under the serial scan); chunk loop is a straight-line 3-deep rotating
// pipeline. Scan/prefix/step math verbatim (bit-identical).
__global__ __launch_bounds__(256, 2) void k_emit(const _Float16* __restrict__ A_sl,
                                                 const float* __restrict__ Bs,
                                                 const _Float16* __restrict__ Mr,
                                                 const float* __restrict__ vch,
                                                 const _Float16* __restrict__ Sr,
                                                 const float* __restrict__ sv,
                                                 float* __restrict__ yb,
                                                 float* __restrict__ out,
                                                 int c0, int scShift) {
  __shared__ float ybuf[128];
  __shared__ float red[128];
  int tid = threadIdx.x;
  int SC = 1 << scShift;
  int NS = SC >> 2;
  int b = blockIdx.x >> scShift;
  int cc = blockIdx.x & (SC - 1);
  int c = c0 + cc;
  int i = tid >> 1, hh = tid & 1;
  int kpre = cc & 3;
  int gsup = cc >> 2;                  // supermap boundary index of the base
  size_t node0 = ((size_t)b << scShift) + (cc & ~3);
  int nst = min(L_, T_ - c * L_);      // 7 or 8
  size_t sidx0 = (size_t)blockIdx.x * L_;
  size_t btb = (size_t)b * T_ + c * L_;

  uint4 arA[8], arB[8], arC[8], arP[8];
  float bsA, bsB, bsC, vvP = 0.f;

#define LOADR(ar, bsv, l)                                                            \
  {                                                                                  \
    const uint4* p = (const uint4*)(A_sl + (sidx0 + (l)) * 16384 + i * 128 + hh * 64); \
    _Pragma("unroll")                                                                \
    for (int u = 0; u < 8; u++) ar[u] = p[u];                                        \
    bsv = Bs[(btb + (l)) * 128 + i];                                                 \
  }

  // hoisted loads: steps 0..2 (always exist, nst >= 7) + prefix j=0.
  // Their ~1us latency hides under the serial supermap scan below.
  LOADR(arA, bsA, 0);
  LOADR(arB, bsB, 1);
  LOADR(arC, bsC, 2);
  if (kpre > 0) {
    const uint4* p2 = (const uint4*)(Mr + node0 * 16384 + i * 128 + hh * 64);
#pragma unroll
    for (int u = 0; u < 8; u++) arP[u] = p2[u];
    vvP = vch[node0 * 128 + i];
  }

  if (tid < 128) ybuf[tid] = yb[(size_t)(b * NC + c0) * 128 + tid];
  __syncthreads();

  // ---- supermap scan (bit-identical chainsuper math, no yb stores) ----
  uint4 sA[8], sB[8];
  float svA, svB;

#define SLOAD(ar, svv, s)                                                            \
  {                                                                                  \
    const uint4* p = (const uint4*)(Sr + (size_t)(b * NS + (s)) * 16384 + i * 128 + hh * 64); \
    _Pragma("unroll")                                                                \
    for (int u = 0; u < 8; u++) ar[u] = p[u];                                        \
    svv = sv[(size_t)(b * NS + (s)) * 128 + i];                                      \
  }

#define SSTEP(ar, svv)                                                               \
  {                                                                                  \
    float pt = 0.f;                                                                  \
    _Pragma("unroll")                                                                \
    for (int u = 0; u < 8; u++) {                                                    \
      union { uint4 v; _Float16 h[8]; } wv; wv.v = ar[u];                            \
      _Pragma("unroll")                                                              \
      for (int k = 0; k < 8; k++) pt += (float)wv.h[k] * ybuf[hh * 64 + u * 8 + k];  \
    }                                                                                \
    if (hh) red[i] = pt;                                                             \
    __syncthreads();                                                                 \
    if (!hh) ybuf[i] = ybuf[i] + pt + red[i] + svv;                                  \
    __syncthreads();                                                                 \
  }

  if (gsup > 0) {
    SLOAD(sA, svA, 0);
    int s = 0;
    for (; s + 1 < gsup; s += 2) {
      SLOAD(sB, svB, s + 1);
      SSTEP(sA, svA);
      if (s + 2 < gsup) SLOAD(sA, svA, s + 2);
      SSTEP(sB, svB);
    }
    if (s < gsup) SSTEP(sA, svA);
  }

  // designated next-slice boundary writer (replicates chainsuper final step)
  if (cc == SC - 4 && c0 + SC < NC) {
    SLOAD(sA, svA, NS - 1);
    float pt = 0.f;
#pragma unroll
    for (int u = 0; u < 8; u++) {
      union { uint4 v; _Float16 h[8]; } wv; wv.v = sA[u];
#pragma unroll
      for (int k = 0; k < 8; k++) pt += (float)wv.h[k] * ybuf[hh * 64 + u * 8 + k];
    }
    if (hh) red[i] = pt;
    __syncthreads();
    if (!hh) yb[(size_t)(b * NC + c0 + SC) * 128 + i] = ybuf[i] + pt + red[i] + svA;
    __syncthreads();
  }
#undef SLOAD
#undef SSTEP

  // ---- prefix: apply kpre chunk maps (unchanged math; j=0 prefetched) ----
  for (int j = 0; j < kpre; j++) {
    uint4 ar[8];
    float vv;
    if (j == 0) {
#pragma unroll
      for (int u = 0; u < 8; u++) ar[u] = arP[u];
      vv = vvP;
    } else {
      const uint4* p = (const uint4*)(Mr + (node0 + j) * 16384 + i * 128 + hh * 64);
#pragma unroll
      for (int u = 0; u < 8; u++) ar[u] = p[u];
      vv = vch[(node0 + j) * 128 + i];
    }
    float pt = 0.f;
#pragma unroll
    for (int u = 0; u < 8; u++) {
      union { uint4 v; _Float16 h[8]; } wv; wv.v = ar[u];
#pragma unroll
      for (int k = 0; k < 8; k++) pt += (float)wv.h[k] * ybuf[hh * 64 + u * 8 + k];
    }
    if (hh) red[i] = pt;
    __syncthreads();
    if (!hh) {
      float yn = ybuf[i] + pt + red[i] + vv;
      ybuf[i] = yn;
    }
    __syncthreads();
  }

  // ---- 8 chunk steps: straight-line 3-deep rotation (math unchanged) ----
#define STEPE(ar, bsv, l)                                                            \
  {                                                                                  \
    float pt = 0.f;                                                                  \
    _Pragma("unroll")                                                                \
    for (int u = 0; u < 8; u++) {                                                    \
      union { uint4 v; _Float16 h[8]; } wv; wv.v = ar[u];                            \
      _Pragma("unroll")                                                              \
      for (int k = 0; k < 8; k++) pt += (float)wv.h[k] * ybuf[hh * 64 + u * 8 + k];  \
    }                                                                                \
    if (hh) red[i] = pt;                                                             \
    __syncthreads();                                                                 \
    if (!hh) {                                                                       \
      float yn = ybuf[i] + pt + red[i] + bsv;                                        \
      out[((size_t)b * S_ + (size_t)(c * L_ + (l) + 1)) * 128 + i] = yn;             \
      ybuf[i] = yn;                                                                  \
    }                                                                                \
    __syncthreads();                                                                 \
  }

  STEPE(arA, bsA, 0); LOADR(arA, bsA, 3);
  STEPE(arB, bsB, 1); LOADR(arB, bsB, 4);
  STEPE(arC, bsC, 2); LOADR(arC, bsC, 5);
  STEPE(arA, bsA, 3); LOADR(arA, bsA, 6);
  STEPE(arB, bsB, 4); if (7 < nst) LOADR(arB, bsB, 7);
  STEPE(arC, bsC, 5);
  STEPE(arA, bsA, 6);
  if (7 < nst) STEPE(arB, bsB, 7);
#undef LOADR
#undef STEPE
}

// ---------------- fallback: plain sequential ----------------
__global__ __launch_bounds__(256) void k_seq(const float* __restrict__ X,
                                             const float* __restrict__ Wa,
                                             const float* __restrict__ Wb,
                                             float* __restrict__ out) {
  int b = blockIdx.x, tid = threadIdx.x;
  int i = tid >> 1, hh = tid & 1;
  __shared__ float y[H_], red[H_], xs[D_], bts[H_];
  if (tid < H_) y[tid] = out[(size_t)b * S_ * H_ + tid];
  __syncthreads();
  for (int t = 1; t < S_; t++) {
    if (tid < D_) xs[tid] = X[((size_t)b * S_ + t) * D_ + tid] * DTC;
    __syncthreads();
    if (tid < H_) {
      const float* wr = Wb + tid * KD;
      float acc = wr[0] * DTC;
#pragma unroll 8
      for (int d = 0; d < D_; d++) acc += xs[d] * wr[1 + d];
      bts[tid] = acc;
    }
    float part = 0.f;
    const float* yhalf = &y[hh * 64];
    for (int j = 0; j < 64; j++) {
      const float* wr = Wa + ((size_t)(i * H_) + hh * 64 + j) * KD;
      float a = wr[0] * DTC;
#pragma unroll 8
      for (int d = 0; d < D_; d++) a += xs[d] * wr[1 + d];
      part += a * yhalf[j];
    }
    if (hh) red[i] = part;
    __syncthreads();
    if (!hh) {
      float yn = y[i] + part + red[i] + bts[i];
      out[((size_t)b * S_ + t) * H_ + i] = yn;
      y[i] = yn;
    }
    __syncthreads();
  }
}

__global__ __launch_bounds__(128) void k_y0f(const float* __restrict__ X,
                                             const float* __restrict__ Wi,
                                             const float* __restrict__ bi,
                                             float* __restrict__ out) {
  int b = blockIdx.x, h = threadIdx.x;
  __shared__ float xs[D_];
  if (h < D_) xs[h] = X[(size_t)b * S_ * D_ + h];
  __syncthreads();
  float acc = bi[h];
  const float* wr = Wi + h * D_;
#pragma unroll 8
  for (int d = 0; d < D_; d++) acc += xs[d] * wr[d];
  out[(size_t)b * S_ * H_ + h] = acc;
}

extern "C" void kernel_launch(void* const* d_in, const int* in_sizes, int n_in,
                              void* d_out, int out_size, void* d_ws, size_t ws_size,
                              hipStream_t stream) {
  (void)in_sizes; (void)n_in; (void)out_size;
  const float* X  = (const float*)d_in[0];
  const float* Wi = (const float*)d_in[1];
  const float* bi = (const float*)d_in[2];
  const float* Wa = (const float*)d_in[3];
  const float* Wb = (const float*)d_in[4];
  float* out = (float*)d_out;
  char* ws = (char*)d_ws;

  size_t off = 0;
  auto alloc = [&](size_t bytes) { size_t o = off; off = (off + bytes + 255) & ~(size_t)255; return o; };
  size_t oBs  = alloc((size_t)B_ * T_ * 128 * 4);       //  8.38 MB
  size_t oYb  = alloc((size_t)B_ * NC * 128 * 4);       //  1.05 MB
  size_t oWaB = alloc((size_t)64 * 16384 * 2);          //  2.10 MB
  size_t oWa0 = alloc((size_t)16384 * 4);
  size_t oXs  = alloc((size_t)B_ * T_ * 64 * 2);        //  2.10 MB
  size_t fixed = off;

  const size_t APC  = (size_t)B_ * L_ * 16384 * 2;      // 2.10 MB
  const size_t MRPC = (size_t)B_ * 16384 * 2;           // 0.26 MB
  const size_t VCPC = (size_t)B_ * 128 * 4;             // 4 KB
  const size_t SRPC = (size_t)B_ * 16384 * 2 / 4;       // 64 KB
  const size_t SVPC = (size_t)B_ * 128;
  const size_t PER_SC = APC + MRPC + VCPC + SRPC + SVPC + 5 * 256;

  int SC = 0;
  if (ws_size > fixed) {
    size_t avail = ws_size - fixed;
    SC = 64;                             // ws=256MiB: SC=128 can never fit
    while (SC >= 4 && (size_t)SC * PER_SC > avail) SC >>= 1;
    if (SC < 4) SC = 0;
  }
  if (SC < 4) {
    k_y0f<<<B_, 128, 0, stream>>>(X, Wi, bi, out);
    k_seq<<<B_, 256, 0, stream>>>(X, Wa, Wb, out);
    return;
  }
  int scShift = __builtin_ctz(SC);

  size_t oMr = alloc((size_t)SC * MRPC);
  size_t oVc = alloc((size_t)SC * VCPC);
  size_t oSr = alloc((size_t)SC * SRPC);
  size_t oSv = alloc((size_t)SC * SVPC);
  size_t oA  = alloc((size_t)SC * APC);

  float*    Bs    = (float*)(ws + oBs);
  float*    yb    = (float*)(ws + oYb);
  _Float16* Wa16B = (_Float16*)(ws + oWaB);
  float*    Wa0   = (float*)(ws + oWa0);
  _Float16* Xs16  = (_Float16*)(ws + oXs);
  _Float16* Mr    = (_Float16*)(ws + oMr);
  float*    vch   = (float*)(ws + oVc);
  _Float16* Sr    = (_Float16*)(ws + oSr);
  float*    sv    = (float*)(ws + oSv);
  _Float16* A_sl  = (_Float16*)(ws + oA);

  // merged prep: Wa swizzle + Xs16 + Bs + y0 in one dispatch
  k_prep<<<9222, 256, 0, stream>>>(Wa, Wa16B, Wa0, X, Xs16, Wb, Bs, Wi, bi, out, yb);

  int nslices = NC / SC;
  int chunks = B_ * SC;
  int amat_gx = (B_ * SC * L_) / 32;
  for (int si = 0; si < nslices; si++) {
    int c0 = si * SC;
    k_amat<<<dim3(amat_gx, 32), 256, 0, stream>>>(Xs16, Wa16B, Wa0, A_sl, c0, scShift);
    k_chunkmap<<<chunks, 256, 0, stream>>>(A_sl, Bs, Mr, vch, c0, scShift);
    k_comp4<<<chunks / 4, 256, 0, stream>>>(Mr, vch, Sr, sv);
    k_emit<<<chunks, 256, 0, stream>>>(A_sl, Bs, Mr, vch, Sr, sv, yb, out, c0, scShift);
  }
}

// Round 7
// 608.115 us; speedup vs baseline: 1.1216x; 1.1216x over previous
//
#include <hip/hip_runtime.h>
#include <hip/hip_fp16.h>

// LinearCDE chunked parallel scan, MFMA edition, adaptive workspace.
//   y_t = y_{t-1} + A_t y_{t-1} + b_t;  A_t = reshape(inp_t @ Wa^T, [H,H])
// R22: barrier-halving, bit-identical. R21 (3-deep reg prefetch) REVERTED:
// VGPR 64->128 + scratch spill (WRITE_SIZE 8x) made emit 56->73us. R20's
// counters show emit is serial-chain-bound (VALU 4.3us of 56us, ~370KB/CU
// moved): the cost is ~2 barriers + an LDS red[] round trip per dependent
// step at 8 waves/CU. Fix, preserving exact fp32 add order:
//   (a) red[] LDS exchange -> __shfl_xor(pt,1) (lanes 2i/2i+1 same wave);
//   (b) double-buffer the serially-updated LDS state (ybuf / Dt+v32):
//       read cur, write cur^1 -> WAR barrier gone, ONE barrier per step.
//       (After a barrier all prior reads are done, so writing the retired
//       buffer is race-free.) chunkmap LDS 35->70KB, still 2 blocks/CU.
// Structure = R18 (best, 607us): prep + 4x(amat,chunkmap,comp4,chainsuper,
// emit), 2-deep register prefetch everywhere.
// History: R16 grid.sync=671, R17 acq_rel=844, R18=607, R19 smap=783,
// R20 emit-scan=615, R21 3-deep=682.

typedef _Float16 h8 __attribute__((ext_vector_type(8)));
typedef float v4f __attribute__((ext_vector_type(4)));
typedef unsigned int uint;

constexpr int B_ = 8, S_ = 2048, D_ = 64, H_ = 128;
constexpr int T_ = S_ - 1;              // 2047
constexpr int KD = D_ + 1;              // 65
constexpr float DTC = 1.0f / 2047.0f;
constexpr int L_ = 8;                   // chunk length
constexpr int LSH = 3;                  // log2(L_)
constexpr int NC = 256;                 // chunks per batch (last has 7 steps)
constexpr int DTS = 128 * 136;          // one Dt buffer (half elements)

// ---------------- k_prep: merged prep ----------------
__global__ __launch_bounds__(256) void k_prep(const float* __restrict__ Wa,
                                              _Float16* __restrict__ Wa16B,
                                              float* __restrict__ Wa0,
                                              const float* __restrict__ X,
                                              _Float16* __restrict__ Xs16,
                                              const float* __restrict__ Wb,
                                              float* __restrict__ Bs,
                                              const float* __restrict__ Wi,
                                              const float* __restrict__ bi,
                                              float* __restrict__ out,
                                              float* __restrict__ yb) {
  __shared__ float wb_s[H_ * KD];
  __shared__ float xs[16][D_ + 4];
  int bx = blockIdx.x, tid = threadIdx.x;
  if (bx < 4096) {
    int idx = bx * 256 + tid;             // 16384*64 exact
    int r = idx >> 6, kk = idx & 63;
    int rt = r >> 4, n = r & 15;
    int kb = kk >> 5, q = (kk >> 3) & 3, jj = kk & 7;
    float v = Wa[(size_t)r * KD + 1 + kk];
    Wa16B[((((size_t)rt * 2 + kb) * 4 + q) * 16 + n) * 8 + jj] = (_Float16)v;
    if (kk == 0) Wa0[r] = Wa[(size_t)r * KD];
  } else if (bx < 8190) {
    int idx = (bx - 4096) * 256 + tid;    // 4094*256 >= B*T*64 exact
    if (idx < B_ * T_ * 64) {
      int bt = idx >> 6, d = idx & 63;
      int b = bt / T_, s = bt - b * T_;
      Xs16[(size_t)bt * 64 + d] = (_Float16)(X[((size_t)b * S_ + s + 1) * D_ + d] * DTC);
    }
  } else if (bx < 9214) {
    int bt0 = (bx - 8190) * 16;
    for (int i2 = tid; i2 < H_ * KD; i2 += 256) wb_s[i2] = Wb[i2];
    for (int i2 = tid; i2 < 16 * D_; i2 += 256) {
      int sl = i2 >> 6, d = i2 & 63;
      int btg = bt0 + sl;
      float v = 0.f;
      if (btg < B_ * T_) {
        int b = btg / T_, s = btg - b * T_;
        v = X[((size_t)b * S_ + s + 1) * D_ + d] * DTC;
      }
      xs[sl][d] = v;
    }
    __syncthreads();
    int h = tid & 127, sh = tid >> 7;
    const float* wrow = &wb_s[h * KD];
    for (int u = 0; u < 8; u++) {
      int sl = sh * 8 + u;
      int btg = bt0 + sl;
      if (btg >= B_ * T_) break;
      float acc = wrow[0] * DTC;
#pragma unroll 8
      for (int d = 0; d < D_; d++) acc += xs[sl][d] * wrow[1 + d];
      Bs[(size_t)btg * H_ + h] = acc;
    }
  } else {
    int b = bx - 9214;
    if (tid < D_) xs[0][tid] = X[(size_t)b * S_ * D_ + tid];
    __syncthreads();
    if (tid < H_) {
      float acc = bi[tid];
      const float* wr = Wi + tid * D_;
#pragma unroll 8
      for (int d = 0; d < D_; d++) acc += xs[0][d] * wr[d];
      out[(size_t)b * S_ * H_ + tid] = acc;
      yb[(size_t)(b * NC + 0) * H_ + tid] = acc;
    }
  }
}

// ---------------- k_amat v2: 32t x 512el tiles, contiguous 1KB writes -----
__global__ __launch_bounds__(256) void k_amat(const _Float16* __restrict__ Xs16,
                                              const _Float16* __restrict__ Wa16B,
                                              const float* __restrict__ Wa0,
                                              _Float16* __restrict__ A_sl,
                                              int c0, int scShift) {
  __shared__ _Float16 sb[32 * 528];    // 33.8 KB
  int tid = threadIdx.x;
  int w = tid >> 6, lane = tid & 63;
  int n = lane & 15, q = lane >> 4;
  int rowbase = blockIdx.x * 32;
  int SCm = ((1 << scShift) << LSH) - 1;

  h8 af[2][2];
#pragma unroll
  for (int mi = 0; mi < 2; mi++) {
    int sidx = rowbase + mi * 16 + n;
    int b = sidx >> (scShift + LSH);
    int rem = sidx & SCm;
    int cc = rem >> LSH, l = rem & (L_ - 1);
    int s = (c0 + cc) * L_ + l;
    if (s >= T_) s = T_ - 1;
    size_t btg = (size_t)b * T_ + s;
#pragma unroll
    for (int kb = 0; kb < 2; kb++)
      af[mi][kb] = *(const h8*)(Xs16 + btg * 64 + kb * 32 + q * 8);
  }

  v4f acc[2][8];
#pragma unroll
  for (int nj = 0; nj < 8; nj++) {
    int ct_g = blockIdx.y * 32 + w * 8 + nj;
    float binit = DTC * Wa0[ct_g * 16 + n];
    h8 bf0 = *(const h8*)(Wa16B + ((((size_t)ct_g * 2 + 0) * 4 + q) * 16 + n) * 8);
    h8 bf1 = *(const h8*)(Wa16B + ((((size_t)ct_g * 2 + 1) * 4 + q) * 16 + n) * 8);
#pragma unroll
    for (int mi = 0; mi < 2; mi++) {
      v4f a;
      a[0] = binit; a[1] = binit; a[2] = binit; a[3] = binit;
      a = __builtin_amdgcn_mfma_f32_16x16x32_f16(af[mi][0], bf0, a, 0, 0, 0);
      a = __builtin_amdgcn_mfma_f32_16x16x32_f16(af[mi][1], bf1, a, 0, 0, 0);
      acc[mi][nj] = a;
    }
  }
#pragma unroll
  for (int mi = 0; mi < 2; mi++)
#pragma unroll
    for (int nj = 0; nj < 8; nj++)
#pragma unroll
      for (int reg = 0; reg < 4; reg++)
        sb[(mi * 16 + q * 4 + reg) * 528 + w * 128 + ((nj * 16 + n) ^ (q * 16))] =
            (_Float16)acc[mi][nj][reg];
  __syncthreads();
#pragma unroll
  for (int it = 0; it < 8; it++) {
    int idx = tid + it * 256;
    int t = idx >> 6, u4 = idx & 63;
    int qt = (t >> 2) & 3;
    uint4 val = *(const uint4*)&sb[t * 528 + ((u4 * 8) ^ (qt * 16))];
    *(uint4*)(A_sl + (size_t)(rowbase + t) * 16384 + blockIdx.y * 512 + u4 * 8) = val;
  }
}

// ---------------- chunkmap body: chunk map via 7 serial compositions ------
// R22: Dt/v32 double-buffered -> ONE barrier per step (WAR gone). Math and
// fp32 add order verbatim from R18.
__device__ __forceinline__ void chunkmap_body(const _Float16* __restrict__ A_sl,
                                              const float* __restrict__ Bs,
                                              _Float16* __restrict__ Mr,
                                              float* __restrict__ vch,
                                              int c0, int scShift, int chunk, int tid,
                                              _Float16* Dt, float* v32) {
  int w = tid >> 6, lane = tid & 63;
  int n = lane & 15, q = lane >> 4;
  int SC = 1 << scShift;
  int b = chunk >> scShift;
  int cc = chunk & (SC - 1);
  int c = c0 + cc;
  int sbase = c * L_;
  int nsteps = min(L_, T_ - sbase);     // 7 or 8
  const _Float16* Abase = A_sl + (size_t)chunk * L_ * 16384;
  size_t btb = (size_t)b * T_ + sbase;

  // stage A0^T into buffer 0 (conflict-free R10 mapping)
#pragma unroll
  for (int it = 0; it < 8; it++) {
    int idx = tid + it * 256;
    int rowl = idx & 127, c8 = (idx >> 7) * 8;
    uint4 pk = *(const uint4*)(Abase + rowl * 128 + c8);
    const _Float16* hp = (const _Float16*)&pk;
#pragma unroll
    for (int cx = 0; cx < 8; cx++) Dt[(c8 + cx) * 136 + rowl] = hp[cx];
  }
  if (tid < 128) v32[tid] = Bs[btb * 128 + tid];
  h8 idE, idO;
#pragma unroll
  for (int jj = 0; jj < 8; jj++) {
    idE[jj] = (_Float16)((q * 8 + jj == n) ? 1.f : 0.f);
    idO[jj] = (_Float16)((q * 8 + jj == 16 + n) ? 1.f : 0.f);
  }
  __syncthreads();

  v4f acc[2][8];
#pragma unroll
  for (int mi = 0; mi < 2; mi++) {
    int row0 = (2 * w + mi) * 16 + q * 4;
#pragma unroll
    for (int nj = 0; nj < 8; nj++) {
      int col = nj * 16 + n;
      union { uint2 u; _Float16 h[4]; } m2;
      m2.u = *(const uint2*)&Dt[col * 136 + row0];
#pragma unroll
      for (int reg = 0; reg < 4; reg++) acc[mi][nj][reg] = (float)m2.h[reg];
    }
  }

  int r0 = 2 * w * 16 + n, r1 = r0 + 16;
  h8 afA[2][4], afB[2][4];   // 2-deep named buffers (R20-proven, no spill)

#define LOADA(dst, l)                                                                \
  {                                                                                  \
    const _Float16* Ag = Abase + (size_t)(l) * 16384;                                \
    _Pragma("unroll")                                                                \
    for (int mi = 0; mi < 2; mi++)                                                   \
      _Pragma("unroll")                                                              \
      for (int kb = 0; kb < 4; kb++)                                                 \
        dst[mi][kb] = *(const h8*)(Ag + ((2 * w + mi) * 16 + n) * 128 + kb * 32 + q * 8); \
  }

#define STEPQ(af, l)                                                                 \
  {                                                                                  \
    int cu_ = ((l) - 1) & 1;                                                         \
    const _Float16* Dr = Dt + cu_ * DTS;                                             \
    _Float16* Dw = Dt + (cu_ ^ 1) * DTS;                                             \
    const float* vr = v32 + cu_ * 128;                                               \
    float* vw = v32 + (cu_ ^ 1) * 128;                                               \
    _Pragma("unroll")                                                                \
    for (int nj = 0; nj < 8; nj++) {                                                 \
      h8 bfr[4];                                                                     \
      _Pragma("unroll")                                                              \
      for (int kb = 0; kb < 4; kb++)                                                 \
        bfr[kb] = *(const h8*)&Dr[(nj * 16 + n) * 136 + kb * 32 + q * 8];            \
      _Pragma("unroll")                                                              \
      for (int mi = 0; mi < 2; mi++) {                                               \
        _Pragma("unroll")                                                            \
        for (int kb = 0; kb < 4; kb++)                                               \
          acc[mi][nj] = __builtin_amdgcn_mfma_f32_16x16x32_f16(af[mi][kb], bfr[kb], acc[mi][nj], 0, 0, 0); \
        acc[mi][nj] = __builtin_amdgcn_mfma_f32_16x16x32_f16(                        \
            af[mi][nj >> 1], (nj & 1) ? idO : idE, acc[mi][nj], 0, 0, 0);            \
      }                                                                              \
    }                                                                                \
    float dv0 = 0.f, dv1 = 0.f;                                                      \
    _Pragma("unroll")                                                                \
    for (int kb = 0; kb < 4; kb++) {                                                 \
      float4 p0 = *(const float4*)&vr[kb * 32 + q * 8];                              \
      float4 p1 = *(const float4*)&vr[kb * 32 + q * 8 + 4];                          \
      float vk[8] = {p0.x, p0.y, p0.z, p0.w, p1.x, p1.y, p1.z, p1.w};                \
      _Pragma("unroll")                                                              \
      for (int jj = 0; jj < 8; jj++) {                                               \
        dv0 += (float)af[0][kb][jj] * vk[jj];                                        \
        dv1 += (float)af[1][kb][jj] * vk[jj];                                        \
      }                                                                              \
    }                                                                                \
    dv0 += __shfl_xor(dv0, 16); dv0 += __shfl_xor(dv0, 32);                          \
    dv1 += __shfl_xor(dv1, 16); dv1 += __shfl_xor(dv1, 32);                          \
    float vold0 = vr[r0], vold1 = vr[r1];                                            \
    float bs0 = 0.f, bs1 = 0.f;                                                      \
    if (q == 0) {                                                                    \
      bs0 = Bs[(btb + (l)) * 128 + r0];                                              \
      bs1 = Bs[(btb + (l)) * 128 + r1];                                              \
    }                                                                                \
    _Pragma("unroll")                                                                \
    for (int mi = 0; mi < 2; mi++) {                                                 \
      int row0 = (2 * w + mi) * 16 + q * 4;                                          \
      _Pragma("unroll")                                                              \
      for (int nj = 0; nj < 8; nj++) {                                               \
        int col = nj * 16 + n;                                                       \
        union { _Float16 h[4]; uint2 u; } pk;                                        \
        _Pragma("unroll")                                                            \
        for (int reg = 0; reg < 4; reg++) pk.h[reg] = (_Float16)acc[mi][nj][reg];    \
        *(uint2*)&Dw[col * 136 + row0] = pk.u;                                       \
      }                                                                              \
    }                                                                                \
    if (q == 0) {                                                                    \
      vw[r0] = vold0 + dv0 + bs0;                                                    \
      vw[r1] = vold1 + dv1 + bs1;                                                    \
    }                                                                                \
    __syncthreads();                                                                 \
  }

  LOADA(afA, 1);
  for (int l = 1; l < nsteps; l += 2) {
    if (l + 1 < nsteps) LOADA(afB, l + 1);
    STEPQ(afA, l);
    if (l + 2 < nsteps) LOADA(afA, l + 2);
    if (l + 1 < nsteps) STEPQ(afB, l + 1);
  }
#undef LOADA
#undef STEPQ

  // tail: acc -> Dt buffer 0 (all waves past last step barrier -> safe)
#pragma unroll
  for (int mi = 0; mi < 2; mi++) {
    int row0 = (2 * w + mi) * 16 + q * 4;
#pragma unroll
    for (int nj = 0; nj < 8; nj++) {
      int col = nj * 16 + n;
#pragma unroll
      for (int reg = 0; reg < 4; reg++)
        Dt[(row0 + reg) * 136 + col] = (_Float16)acc[mi][nj][reg];
    }
  }
  __syncthreads();
  _Float16* og = Mr + (size_t)chunk * 16384;
#pragma unroll
  for (int it = 0; it < 8; it++) {
    int idx = tid + it * 256;
    int rowl = idx >> 4, ch = idx & 15;
    uint4 val = *(const uint4*)&Dt[rowl * 136 + ch * 8];
    *(uint4*)(og + rowl * 128 + ch * 8) = val;
  }
  if (tid < 128) vch[(size_t)chunk * 128 + tid] = v32[((nsteps - 1) & 1) * 128 + tid];
}

// ---------------- comp4 body: compose 4 consecutive delta maps ------------
// R22: same double-buffer single-barrier treatment (j = 1..3; parity (j-1)&1).
__device__ __forceinline__ void comp4_body(const _Float16* __restrict__ in_map,
                                           const float* __restrict__ in_v,
                                           _Float16* __restrict__ out_map,
                                           float* __restrict__ out_v,
                                           int outIdx, int tid,
                                           _Float16* Dt, float* v32) {
  int w = tid >> 6, lane = tid & 63;
  int n = lane & 15, q = lane >> 4;
  size_t nbase = (size_t)outIdx * 4;

  const _Float16* P0 = in_map + nbase * 16384;
#pragma unroll
  for (int it = 0; it < 8; it++) {
    int idx = tid + it * 256;
    int rowl = idx & 127, c8 = (idx >> 7) * 8;
    uint4 pk = *(const uint4*)(P0 + rowl * 128 + c8);
    const _Float16* hp = (const _Float16*)&pk;
#pragma unroll
    for (int cx = 0; cx < 8; cx++) Dt[(c8 + cx) * 136 + rowl] = hp[cx];
  }
  if (tid < 128) v32[tid] = in_v[nbase * 128 + tid];
  h8 idE, idO;
#pragma unroll
  for (int jj = 0; jj < 8; jj++) {
    idE[jj] = (_Float16)((q * 8 + jj == n) ? 1.f : 0.f);
    idO[jj] = (_Float16)((q * 8 + jj == 16 + n) ? 1.f : 0.f);
  }
  __syncthreads();

  v4f acc[2][8];
#pragma unroll
  for (int mi = 0; mi < 2; mi++) {
    int row0 = (2 * w + mi) * 16 + q * 4;
#pragma unroll
    for (int nj = 0; nj < 8; nj++) {
      int col = nj * 16 + n;
      union { uint2 u; _Float16 h[4]; } m2;
      m2.u = *(const uint2*)&Dt[col * 136 + row0];
#pragma unroll
      for (int reg = 0; reg < 4; reg++) acc[mi][nj][reg] = (float)m2.h[reg];
    }
  }

  int r0 = 2 * w * 16 + n, r1 = r0 + 16;
  for (int j = 1; j < 4; j++) {
    int cu_ = (j - 1) & 1;
    const _Float16* Dr = Dt + cu_ * DTS;
    _Float16* Dw = Dt + (cu_ ^ 1) * DTS;
    const float* vr = v32 + cu_ * 128;
    float* vw = v32 + (cu_ ^ 1) * 128;
    const _Float16* Pj = in_map + (nbase + j) * 16384;
    h8 af[2][4];
#pragma unroll
    for (int mi = 0; mi < 2; mi++)
#pragma unroll
      for (int kb = 0; kb < 4; kb++)
        af[mi][kb] = *(const h8*)(Pj + ((2 * w + mi) * 16 + n) * 128 + kb * 32 + q * 8);
#pragma unroll
    for (int nj = 0; nj < 8; nj++) {
      h8 bfr[4];
#pragma unroll
      for (int kb = 0; kb < 4; kb++)
        bfr[kb] = *(const h8*)&Dr[(nj * 16 + n) * 136 + kb * 32 + q * 8];
#pragma unroll
      for (int mi = 0; mi < 2; mi++) {
#pragma unroll
        for (int kb = 0; kb < 4; kb++)
          acc[mi][nj] = __builtin_amdgcn_mfma_f32_16x16x32_f16(af[mi][kb], bfr[kb], acc[mi][nj], 0, 0, 0);
        acc[mi][nj] = __builtin_amdgcn_mfma_f32_16x16x32_f16(
            af[mi][nj >> 1], (nj & 1) ? idO : idE, acc[mi][nj], 0, 0, 0);
      }
    }
    float dv0 = 0.f, dv1 = 0.f;
#pragma unroll
    for (int kb = 0; kb < 4; kb++) {
      float4 p0 = *(const float4*)&vr[kb * 32 + q * 8];
      float4 p1 = *(const float4*)&vr[kb * 32 + q * 8 + 4];
      float vk[8] = {p0.x, p0.y, p0.z, p0.w, p1.x, p1.y, p1.z, p1.w};
#pragma unroll
      for (int jj = 0; jj < 8; jj++) {
        dv0 += (float)af[0][kb][jj] * vk[jj];
        dv1 += (float)af[1][kb][jj] * vk[jj];
      }
    }
    dv0 += __shfl_xor(dv0, 16); dv0 += __shfl_xor(dv0, 32);
    dv1 += __shfl_xor(dv1, 16); dv1 += __shfl_xor(dv1, 32);
    float vold0 = vr[r0], vold1 = vr[r1];
    float vj0 = 0.f, vj1 = 0.f;
    if (q == 0) {
      vj0 = in_v[(nbase + j) * 128 + r0];
      vj1 = in_v[(nbase + j) * 128 + r1];
    }
#pragma unroll
    for (int mi = 0; mi < 2; mi++) {
      int row0 = (2 * w + mi) * 16 + q * 4;
#pragma unroll
      for (int nj = 0; nj < 8; nj++) {
        int col = nj * 16 + n;
        union { _Float16 h[4]; uint2 u; } pk;
#pragma unroll
        for (int reg = 0; reg < 4; reg++) pk.h[reg] = (_Float16)acc[mi][nj][reg];
        *(uint2*)&Dw[col * 136 + row0] = pk.u;
      }
    }
    if (q == 0) {
      vw[r0] = vold0 + dv0 + vj0;
      vw[r1] = vold1 + dv1 + vj1;
    }
    __syncthreads();
  }
  // tail: final parity after j=3 is buffer 1; stage acc into buffer 0
#pragma unroll
  for (int mi = 0; mi < 2; mi++) {
    int row0 = (2 * w + mi) * 16 + q * 4;
#pragma unroll
    for (int nj = 0; nj < 8; nj++) {
      int col = nj * 16 + n;
#pragma unroll
      for (int reg = 0; reg < 4; reg++)
        Dt[(row0 + reg) * 136 + col] = (_Float16)acc[mi][nj][reg];
    }
  }
  __syncthreads();
  _Float16* og = out_map + (size_t)outIdx * 16384;
#pragma unroll
  for (int it = 0; it < 8; it++) {
    int idx = tid + it * 256;
    int rowl = idx >> 4, ch = idx & 15;
    uint4 val = *(const uint4*)&Dt[rowl * 136 + ch * 8];
    *(uint4*)(og + rowl * 128 + ch * 8) = val;
  }
  if (tid < 128) out_v[(size_t)outIdx * 128 + tid] = v32[128 + tid];
}

// ---------------- chainsuper body: serial scan over supermaps -------------
// R22: ybuf double-buffered + shfl_xor cross-half reduce; one barrier/step.
__device__ __forceinline__ void chainsuper_body(const _Float16* __restrict__ Sr,
                                                const float* __restrict__ sv,
                                                float* __restrict__ yb,
                                                int c0, int scShift, int b, int tid,
                                                float* ybuf2) {
  int NS = 1 << (scShift - 2);
  int i = tid >> 1, hh = tid & 1;
  if (tid < 128) ybuf2[tid] = yb[(size_t)(b * NC + c0) * 128 + tid];
  __syncthreads();
  int cur = 0;

  uint4 arA[8], arB[8];
  float svA, svB;

#define LOADS(ar, svv, s)                                                            \
  {                                                                                  \
    const uint4* p = (const uint4*)(Sr + (size_t)(b * NS + (s)) * 16384 + i * 128 + hh * 64); \
    _Pragma("unroll")                                                                \
    for (int u = 0; u < 8; u++) ar[u] = p[u];                                        \
    svv = sv[(size_t)(b * NS + (s)) * 128 + i];                                      \
  }

#define STEPS(ar, svv, s)                                                            \
  {                                                                                  \
    const float* yr = ybuf2 + cur * 128;                                             \
    float* yw = ybuf2 + (cur ^ 1) * 128;                                             \
    float pt = 0.f;                                                                  \
    _Pragma("unroll")                                                                \
    for (int u = 0; u < 8; u++) {                                                    \
      union { uint4 v; _Float16 h[8]; } wv; wv.v = ar[u];                            \
      _Pragma("unroll")                                                              \
      for (int k = 0; k < 8; k++) pt += (float)wv.h[k] * yr[hh * 64 + u * 8 + k];    \
    }                                                                                \
    float ptO = __shfl_xor(pt, 1);                                                   \
    if (!hh) {                                                                       \
      float yn = yr[i] + pt;                                                         \
      yn = yn + ptO;                                                                 \
      yn = yn + svv;                                                                 \
      int cg = c0 + 4 * ((s) + 1);                                                   \
      if (cg < NC) yb[(size_t)(b * NC + cg) * 128 + i] = yn;                         \
      yw[i] = yn;                                                                    \
    }                                                                                \
    cur ^= 1;                                                                        \
    __syncthreads();                                                                 \
  }

  LOADS(arA, svA, 0);
  int s = 0;
  for (; s + 1 < NS; s += 2) {
    LOADS(arB, svB, s + 1);
    STEPS(arA, svA, s);
    if (s + 2 < NS) LOADS(arA, svA, s + 2);
    STEPS(arB, svB, s + 1);
  }
  if (s < NS) STEPS(arA, svA, s);
#undef LOADS
#undef STEPS
}

// ---------------- emit body (prefix matvecs + 8 chunk steps) --------------
// R22: ybuf double-buffered + shfl_xor reduce; one barrier/step. Add order
// preserved: ((ybuf + pt_own) + pt_other) + b  ==  old ((ybuf+pt)+red)+b.
__device__ __forceinline__ void emit_body(const _Float16* __restrict__ A_sl,
                                          const float* __restrict__ Bs,
                                          const _Float16* __restrict__ Mr,
                                          const float* __restrict__ vch,
                                          const float* __restrict__ yb,
                                          float* __restrict__ out,
                                          int tid, int b, int c, int kpre, int cbase,
                                          int nst, size_t node0, size_t sidx0, size_t btb,
                                          uint4* arA, float bsA, uint4* arP, float vvP,
                                          float* ybuf2) {
  int i = tid >> 1, hh = tid & 1;
  if (tid < 128) ybuf2[tid] = yb[(size_t)(b * NC + cbase) * 128 + tid];
  __syncthreads();
  int cur = 0;

  // prefix: apply kpre chunk maps (same op order as before)
  for (int j = 0; j < kpre; j++) {
    uint4 ar[8];
    float vv;
    if (j == 0) {
#pragma unroll
      for (int u = 0; u < 8; u++) ar[u] = arP[u];
      vv = vvP;
    } else {
      const uint4* p = (const uint4*)(Mr + (node0 + j) * 16384 + i * 128 + hh * 64);
#pragma unroll
      for (int u = 0; u < 8; u++) ar[u] = p[u];
      vv = vch[(node0 + j) * 128 + i];
    }
    const float* yr = ybuf2 + cur * 128;
    float* yw = ybuf2 + (cur ^ 1) * 128;
    float pt = 0.f;
#pragma unroll
    for (int u = 0; u < 8; u++) {
      union { uint4 v; _Float16 h[8]; } wv; wv.v = ar[u];
#pragma unroll
      for (int k = 0; k < 8; k++) pt += (float)wv.h[k] * yr[hh * 64 + u * 8 + k];
    }
    float ptO = __shfl_xor(pt, 1);
    if (!hh) {
      float yn = yr[i] + pt;
      yn = yn + ptO;
      yn = yn + vv;
      yw[i] = yn;
    }
    cur ^= 1;
    __syncthreads();
  }

  uint4 arB[8];
  float bsB;

#define LOADR(ar, bsv, l)                                                            \
  {                                                                                  \
    const uint4* p = (const uint4*)(A_sl + (sidx0 + (l)) * 16384 + i * 128 + hh * 64); \
    _Pragma("unroll")                                                                \
    for (int u = 0; u < 8; u++) ar[u] = p[u];                                        \
    bsv = Bs[(btb + (l)) * 128 + i];                                                 \
  }

#define STEPE(ar, bsv, l)                                                            \
  {                                                                                  \
    const float* yr = ybuf2 + cur * 128;                                             \
    float* yw = ybuf2 + (cur ^ 1) * 128;                                             \
    float pt = 0.f;                                                                  \
    _Pragma("unroll")                                                                \
    for (int u = 0; u < 8; u++) {                                                    \
      union { uint4 v; _Float16 h[8]; } wv; wv.v = ar[u];                            \
      _Pragma("unroll")                                                              \
      for (int k = 0; k < 8; k++) pt += (float)wv.h[k] * yr[hh * 64 + u * 8 + k];    \
    }                                                                                \
    float ptO = __shfl_xor(pt, 1);                                                   \
    if (!hh) {                                                                       \
      float yn = yr[i] + pt;                                                         \
      yn = yn + ptO;                                                                 \
      yn = yn + bsv;                                                                 \
      out[((size_t)b * S_ + (size_t)(c * L_ + (l) + 1)) * 128 + i] = yn;             \
      yw[i] = yn;                                                                    \
    }                                                                                \
    cur ^= 1;                                                                        \
    __syncthreads();                                                                 \
  }

  // arA already holds step 0 (prefetched); 2-deep rotation (R20-proven)
  for (int l = 0; l < nst; l += 2) {
    if (l + 1 < nst) LOADR(arB, bsB, l + 1);
    STEPE(arA, bsA, l);
    if (l + 2 < nst) LOADR(arA, bsA, l + 2);
    if (l + 1 < nst) STEPE(arB, bsB, l + 1);
  }
#undef LOADR
#undef STEPE
}

// ---------------- standalone stage kernels ----------------
__global__ __launch_bounds__(256) void k_chunkmap(const _Float16* __restrict__ A_sl,
                                                  const float* __restrict__ Bs,
                                                  _Float16* __restrict__ Mr,
                                                  float* __restrict__ vch,
                                                  int c0, int scShift) {
  __shared__ _Float16 Dt[2 * DTS];      // 69.6 KB (double buffer)
  __shared__ float v32[2 * 128];
  chunkmap_body(A_sl, Bs, Mr, vch, c0, scShift, blockIdx.x, threadIdx.x, Dt, v32);
}

__global__ __launch_bounds__(256) void k_comp4(const _Float16* __restrict__ in_map,
                                               const float* __restrict__ in_v,
                                               _Float16* __restrict__ out_map,
                                               float* __restrict__ out_v) {
  __shared__ _Float16 Dt[2 * DTS];
  __shared__ float v32[2 * 128];
  comp4_body(in_map, in_v, out_map, out_v, blockIdx.x, threadIdx.x, Dt, v32);
}

__global__ __launch_bounds__(256) void k_chainsuper(const _Float16* __restrict__ Sr,
                                                    const float* __restrict__ sv,
                                                    float* __restrict__ yb,
                                                    int c0, int scShift) {
  __shared__ float ybuf2[2 * 128];
  chainsuper_body(Sr, sv, yb, c0, scShift, blockIdx.x, threadIdx.x, ybuf2);
}

__global__ __launch_bounds__(256) void k_emit(const _Float16* __restrict__ A_sl,
                                              const float* __restrict__ Bs,
                                              const _Float16* __restrict__ Mr,
                                              const float* __restrict__ vch,
                                              const float* __restrict__ yb,
                                              float* __restrict__ out,
                                              int c0, int scShift) {
  __shared__ float ybuf2[2 * 128];
  int tid = threadIdx.x;
  int SC = 1 << scShift;
  int b = blockIdx.x >> scShift;
  int cc = blockIdx.x & (SC - 1);
  int c = c0 + cc;
  int i = tid >> 1, hh = tid & 1;
  int kpre = cc & 3;
  int cbase = c - kpre;
  size_t node0 = ((size_t)b << scShift) + (cc & ~3);
  int nst = min(L_, T_ - c * L_);
  size_t sidx0 = (size_t)blockIdx.x * L_;
  size_t btb = (size_t)b * T_ + c * L_;
  uint4 arA[8], arP[8];
  float bsA, vvP = 0.f;
  {
    const uint4* p = (const uint4*)(A_sl + sidx0 * 16384 + i * 128 + hh * 64);
#pragma unroll
    for (int u = 0; u < 8; u++) arA[u] = p[u];
    bsA = Bs[btb * 128 + i];
  }
  if (kpre > 0) {
    const uint4* p2 = (const uint4*)(Mr + node0 * 16384 + i * 128 + hh * 64);
#pragma unroll
    for (int u = 0; u < 8; u++) arP[u] = p2[u];
    vvP = vch[node0 * 128 + i];
  }
  emit_body(A_sl, Bs, Mr, vch, yb, out, tid, b, c, kpre, cbase, nst, node0, sidx0, btb,
            arA, bsA, arP, vvP, ybuf2);
}

// ---------------- fallback: plain sequential ----------------
__global__ __launch_bounds__(256) void k_seq(const float* __restrict__ X,
                                             const float* __restrict__ Wa,
                                             const float* __restrict__ Wb,
                                             float* __restrict__ out) {
  int b = blockIdx.x, tid = threadIdx.x;
  int i = tid >> 1, hh = tid & 1;
  __shared__ float y[H_], red[H_], xs[D_], bts[H_];
  if (tid < H_) y[tid] = out[(size_t)b * S_ * H_ + tid];
  __syncthreads();
  for (int t = 1; t < S_; t++) {
    if (tid < D_) xs[tid] = X[((size_t)b * S_ + t) * D_ + tid] * DTC;
    __syncthreads();
    if (tid < H_) {
      const float* wr = Wb + tid * KD;
      float acc = wr[0] * DTC;
#pragma unroll 8
      for (int d = 0; d < D_; d++) acc += xs[d] * wr[1 + d];
      bts[tid] = acc;
    }
    float part = 0.f;
    const float* yhalf = &y[hh * 64];
    for (int j = 0; j < 64; j++) {
      const float* wr = Wa + ((size_t)(i * H_) + hh * 64 + j) * KD;
      float a = wr[0] * DTC;
#pragma unroll 8
      for (int d = 0; d < D_; d++) a += xs[d] * wr[1 + d];
      part += a * yhalf[j];
    }
    if (hh) red[i] = part;
    __syncthreads();
    if (!hh) {
      float yn = y[i] + part + red[i] + bts[i];
      out[((size_t)b * S_ + t) * H_ + i] = yn;
      y[i] = yn;
    }
    __syncthreads();
  }
}

__global__ __launch_bounds__(128) void k_y0f(const float* __restrict__ X,
                                             const float* __restrict__ Wi,
                                             const float* __restrict__ bi,
                                             float* __restrict__ out) {
  int b = blockIdx.x, h = threadIdx.x;
  __shared__ float xs[D_];
  if (h < D_) xs[h] = X[(size_t)b * S_ * D_ + h];
  __syncthreads();
  float acc = bi[h];
  const float* wr = Wi + h * D_;
#pragma unroll 8
  for (int d = 0; d < D_; d++) acc += xs[d] * wr[d];
  out[(size_t)b * S_ * H_ + h] = acc;
}

extern "C" void kernel_launch(void* const* d_in, const int* in_sizes, int n_in,
                              void* d_out, int out_size, void* d_ws, size_t ws_size,
                              hipStream_t stream) {
  (void)in_sizes; (void)n_in; (void)out_size;
  const float* X  = (const float*)d_in[0];
  const float* Wi = (const float*)d_in[1];
  const float* bi = (const float*)d_in[2];
  const float* Wa = (const float*)d_in[3];
  const float* Wb = (const float*)d_in[4];
  float* out = (float*)d_out;
  char* ws = (char*)d_ws;

  size_t off = 0;
  auto alloc = [&](size_t bytes) { size_t o = off; off = (off + bytes + 255) & ~(size_t)255; return o; };
  size_t oBs  = alloc((size_t)B_ * T_ * 128 * 4);       //  8.38 MB
  size_t oYb  = alloc((size_t)B_ * NC * 128 * 4);       //  1.05 MB
  size_t oWaB = alloc((size_t)64 * 16384 * 2);          //  2.10 MB
  size_t oWa0 = alloc((size_t)16384 * 4);
  size_t oXs  = alloc((size_t)B_ * T_ * 64 * 2);        //  2.10 MB
  size_t fixed = off;

  const size_t APC  = (size_t)B_ * L_ * 16384 * 2;      // 2.10 MB
  const size_t MRPC = (size_t)B_ * 16384 * 2;           // 0.26 MB
  const size_t VCPC = (size_t)B_ * 128 * 4;             // 4 KB
  const size_t SRPC = (size_t)B_ * 16384 * 2 / 4;       // 64 KB
  const size_t SVPC = (size_t)B_ * 128;
  const size_t PER_SC = APC + MRPC + VCPC + SRPC + SVPC + 5 * 256;

  int SC = 0;
  if (ws_size > fixed) {
    size_t avail = ws_size - fixed;
    SC = 64;                             // ws=256MiB: SC=128 can never fit
    while (SC >= 4 && (size_t)SC * PER_SC > avail) SC >>= 1;
    if (SC < 4) SC = 0;
  }
  if (SC < 4) {
    k_y0f<<<B_, 128, 0, stream>>>(X, Wi, bi, out);
    k_seq<<<B_, 256, 0, stream>>>(X, Wa, Wb, out);
    return;
  }
  int scShift = __builtin_ctz(SC);

  size_t oMr = alloc((size_t)SC * MRPC);
  size_t oVc = alloc((size_t)SC * VCPC);
  size_t oSr = alloc((size_t)SC * SRPC);
  size_t oSv = alloc((size_t)SC * SVPC);
  size_t oA  = alloc((size_t)SC * APC);

  float*    Bs    = (float*)(ws + oBs);
  float*    yb    = (float*)(ws + oYb);
  _Float16* Wa16B = (_Float16*)(ws + oWaB);
  float*    Wa0   = (float*)(ws + oWa0);
  _Float16* Xs16  = (_Float16*)(ws + oXs);
  _Float16* Mr    = (_Float16*)(ws + oMr);
  float*    vch   = (float*)(ws + oVc);
  _Float16* Sr    = (_Float16*)(ws + oSr);
  float*    sv    = (float*)(ws + oSv);
  _Float16* A_sl  = (_Float16*)(ws + oA);

  // merged prep: Wa swizzle + Xs16 + Bs + y0 in one dispatch
  k_prep<<<9222, 256, 0, stream>>>(Wa, Wa16B, Wa0, X, Xs16, Wb, Bs, Wi, bi, out, yb);

  int nslices = NC / SC;
  int chunks = B_ * SC;
  int amat_gx = (B_ * SC * L_) / 32;
  for (int si = 0; si < nslices; si++) {
    int c0 = si * SC;
    k_amat<<<dim3(amat_gx, 32), 256, 0, stream>>>(Xs16, Wa16B, Wa0, A_sl, c0, scShift);
    k_chunkmap<<<chunks, 256, 0, stream>>>(A_sl, Bs, Mr, vch, c0, scShift);
    k_comp4<<<chunks / 4, 256, 0, stream>>>(Mr, vch, Sr, sv);
    k_chainsuper<<<B_, 256, 0, stream>>>(Sr, sv, yb, c0, scShift);
    k_emit<<<chunks, 256, 0, stream>>>(A_sl, Bs, Mr, vch, yb, out, c0, scShift);
  }
}

// Round 9
// 597.542 us; speedup vs baseline: 1.1414x; 1.0177x over previous
//
#include <hip/hip_runtime.h>
#include <hip/hip_fp16.h>

// LinearCDE chunked parallel scan, MFMA edition, adaptive workspace.
//   y_t = y_{t-1} + A_t y_{t-1} + b_t;  A_t = reshape(inp_t @ Wa^T, [H,H])
// R24 = R23 with the macro compile error fixed (stray 2-arg LOADR removed).
// Theory: emit wave-parallelism attack. R22 (barrier halving) was NEUTRAL ->
// per-step sync is not the pacer. All pipeline kernels <=40us; emit/chunkmap
// stream 134MB/slice at only ~3.5 TB/s vs 6.4 achievable (fills). emit runs
// 2 blocks/CU x 4 waves = 8 waves/CU with one 32KB load-wave per step
// barrier -> load-latency paced at low TLP. Fix: k_emit rebuilt as
// 512-thread blocks, 4 lanes/row (dot-32 per lane): waves/CU 8->16, and
// the lighter 16-VGPR buffers allow a 3-deep rotation + hoisted steps 0-2
// and prefix-j0 (no R21 spill: ~100 VGPR, launch_bounds(512,4) caps 128).
// NOT bit-identical: fp32 dot summed as 4x(dot-32) pairwise-combined vs
// 2x(dot-64)+pair -- same product set, reorder only; absmax drift <<1e-3.
// All other kernels verbatim R22 (= baseline 608).
// History: R16 grid.sync=671, R17 acq_rel=844, R18=607, R19 smap=783,
// R20 emit-scan=615, R21 3-deep-spill=682, R22 barrier-half=608, R23 CE.

typedef _Float16 h8 __attribute__((ext_vector_type(8)));
typedef float v4f __attribute__((ext_vector_type(4)));
typedef unsigned int uint;

constexpr int B_ = 8, S_ = 2048, D_ = 64, H_ = 128;
constexpr int T_ = S_ - 1;              // 2047
constexpr int KD = D_ + 1;              // 65
constexpr float DTC = 1.0f / 2047.0f;
constexpr int L_ = 8;                   // chunk length
constexpr int LSH = 3;                  // log2(L_)
constexpr int NC = 256;                 // chunks per batch (last has 7 steps)
constexpr int DTS = 128 * 136;          // one Dt buffer (half elements)

// ---------------- k_prep: merged prep ----------------
__global__ __launch_bounds__(256) void k_prep(const float* __restrict__ Wa,
                                              _Float16* __restrict__ Wa16B,
                                              float* __restrict__ Wa0,
                                              const float* __restrict__ X,
                                              _Float16* __restrict__ Xs16,
                                              const float* __restrict__ Wb,
                                              float* __restrict__ Bs,
                                              const float* __restrict__ Wi,
                                              const float* __restrict__ bi,
                                              float* __restrict__ out,
                                              float* __restrict__ yb) {
  __shared__ float wb_s[H_ * KD];
  __shared__ float xs[16][D_ + 4];
  int bx = blockIdx.x, tid = threadIdx.x;
  if (bx < 4096) {
    int idx = bx * 256 + tid;             // 16384*64 exact
    int r = idx >> 6, kk = idx & 63;
    int rt = r >> 4, n = r & 15;
    int kb = kk >> 5, q = (kk >> 3) & 3, jj = kk & 7;
    float v = Wa[(size_t)r * KD + 1 + kk];
    Wa16B[((((size_t)rt * 2 + kb) * 4 + q) * 16 + n) * 8 + jj] = (_Float16)v;
    if (kk == 0) Wa0[r] = Wa[(size_t)r * KD];
  } else if (bx < 8190) {
    int idx = (bx - 4096) * 256 + tid;    // 4094*256 >= B*T*64 exact
    if (idx < B_ * T_ * 64) {
      int bt = idx >> 6, d = idx & 63;
      int b = bt / T_, s = bt - b * T_;
      Xs16[(size_t)bt * 64 + d] = (_Float16)(X[((size_t)b * S_ + s + 1) * D_ + d] * DTC);
    }
  } else if (bx < 9214) {
    int bt0 = (bx - 8190) * 16;
    for (int i2 = tid; i2 < H_ * KD; i2 += 256) wb_s[i2] = Wb[i2];
    for (int i2 = tid; i2 < 16 * D_; i2 += 256) {
      int sl = i2 >> 6, d = i2 & 63;
      int btg = bt0 + sl;
      float v = 0.f;
      if (btg < B_ * T_) {
        int b = btg / T_, s = btg - b * T_;
        v = X[((size_t)b * S_ + s + 1) * D_ + d] * DTC;
      }
      xs[sl][d] = v;
    }
    __syncthreads();
    int h = tid & 127, sh = tid >> 7;
    const float* wrow = &wb_s[h * KD];
    for (int u = 0; u < 8; u++) {
      int sl = sh * 8 + u;
      int btg = bt0 + sl;
      if (btg >= B_ * T_) break;
      float acc = wrow[0] * DTC;
#pragma unroll 8
      for (int d = 0; d < D_; d++) acc += xs[sl][d] * wrow[1 + d];
      Bs[(size_t)btg * H_ + h] = acc;
    }
  } else {
    int b = bx - 9214;
    if (tid < D_) xs[0][tid] = X[(size_t)b * S_ * D_ + tid];
    __syncthreads();
    if (tid < H_) {
      float acc = bi[tid];
      const float* wr = Wi + tid * D_;
#pragma unroll 8
      for (int d = 0; d < D_; d++) acc += xs[0][d] * wr[d];
      out[(size_t)b * S_ * H_ + tid] = acc;
      yb[(size_t)(b * NC + 0) * H_ + tid] = acc;
    }
  }
}

// ---------------- k_amat v2: 32t x 512el tiles, contiguous 1KB writes -----
__global__ __launch_bounds__(256) void k_amat(const _Float16* __restrict__ Xs16,
                                              const _Float16* __restrict__ Wa16B,
                                              const float* __restrict__ Wa0,
                                              _Float16* __restrict__ A_sl,
                                              int c0, int scShift) {
  __shared__ _Float16 sb[32 * 528];    // 33.8 KB
  int tid = threadIdx.x;
  int w = tid >> 6, lane = tid & 63;
  int n = lane & 15, q = lane >> 4;
  int rowbase = blockIdx.x * 32;
  int SCm = ((1 << scShift) << LSH) - 1;

  h8 af[2][2];
#pragma unroll
  for (int mi = 0; mi < 2; mi++) {
    int sidx = rowbase + mi * 16 + n;
    int b = sidx >> (scShift + LSH);
    int rem = sidx & SCm;
    int cc = rem >> LSH, l = rem & (L_ - 1);
    int s = (c0 + cc) * L_ + l;
    if (s >= T_) s = T_ - 1;
    size_t btg = (size_t)b * T_ + s;
#pragma unroll
    for (int kb = 0; kb < 2; kb++)
      af[mi][kb] = *(const h8*)(Xs16 + btg * 64 + kb * 32 + q * 8);
  }

  v4f acc[2][8];
#pragma unroll
  for (int nj = 0; nj < 8; nj++) {
    int ct_g = blockIdx.y * 32 + w * 8 + nj;
    float binit = DTC * Wa0[ct_g * 16 + n];
    h8 bf0 = *(const h8*)(Wa16B + ((((size_t)ct_g * 2 + 0) * 4 + q) * 16 + n) * 8);
    h8 bf1 = *(const h8*)(Wa16B + ((((size_t)ct_g * 2 + 1) * 4 + q) * 16 + n) * 8);
#pragma unroll
    for (int mi = 0; mi < 2; mi++) {
      v4f a;
      a[0] = binit; a[1] = binit; a[2] = binit; a[3] = binit;
      a = __builtin_amdgcn_mfma_f32_16x16x32_f16(af[mi][0], bf0, a, 0, 0, 0);
      a = __builtin_amdgcn_mfma_f32_16x16x32_f16(af[mi][1], bf1, a, 0, 0, 0);
      acc[mi][nj] = a;
    }
  }
#pragma unroll
  for (int mi = 0; mi < 2; mi++)
#pragma unroll
    for (int nj = 0; nj < 8; nj++)
#pragma unroll
      for (int reg = 0; reg < 4; reg++)
        sb[(mi * 16 + q * 4 + reg) * 528 + w * 128 + ((nj * 16 + n) ^ (q * 16))] =
            (_Float16)acc[mi][nj][reg];
  __syncthreads();
#pragma unroll
  for (int it = 0; it < 8; it++) {
    int idx = tid + it * 256;
    int t = idx >> 6, u4 = idx & 63;
    int qt = (t >> 2) & 3;
    uint4 val = *(const uint4*)&sb[t * 528 + ((u4 * 8) ^ (qt * 16))];
    *(uint4*)(A_sl + (size_t)(rowbase + t) * 16384 + blockIdx.y * 512 + u4 * 8) = val;
  }
}

// ---------------- chunkmap body (R22: double-buffer, one barrier/step) ----
__device__ __forceinline__ void chunkmap_body(const _Float16* __restrict__ A_sl,
                                              const float* __restrict__ Bs,
                                              _Float16* __restrict__ Mr,
                                              float* __restrict__ vch,
                                              int c0, int scShift, int chunk, int tid,
                                              _Float16* Dt, float* v32) {
  int w = tid >> 6, lane = tid & 63;
  int n = lane & 15, q = lane >> 4;
  int SC = 1 << scShift;
  int b = chunk >> scShift;
  int cc = chunk & (SC - 1);
  int c = c0 + cc;
  int sbase = c * L_;
  int nsteps = min(L_, T_ - sbase);     // 7 or 8
  const _Float16* Abase = A_sl + (size_t)chunk * L_ * 16384;
  size_t btb = (size_t)b * T_ + sbase;

  // stage A0^T into buffer 0 (conflict-free R10 mapping)
#pragma unroll
  for (int it = 0; it < 8; it++) {
    int idx = tid + it * 256;
    int rowl = idx & 127, c8 = (idx >> 7) * 8;
    uint4 pk = *(const uint4*)(Abase + rowl * 128 + c8);
    const _Float16* hp = (const _Float16*)&pk;
#pragma unroll
    for (int cx = 0; cx < 8; cx++) Dt[(c8 + cx) * 136 + rowl] = hp[cx];
  }
  if (tid < 128) v32[tid] = Bs[btb * 128 + tid];
  h8 idE, idO;
#pragma unroll
  for (int jj = 0; jj < 8; jj++) {
    idE[jj] = (_Float16)((q * 8 + jj == n) ? 1.f : 0.f);
    idO[jj] = (_Float16)((q * 8 + jj == 16 + n) ? 1.f : 0.f);
  }
  __syncthreads();

  v4f acc[2][8];
#pragma unroll
  for (int mi = 0; mi < 2; mi++) {
    int row0 = (2 * w + mi) * 16 + q * 4;
#pragma unroll
    for (int nj = 0; nj < 8; nj++) {
      int col = nj * 16 + n;
      union { uint2 u; _Float16 h[4]; } m2;
      m2.u = *(const uint2*)&Dt[col * 136 + row0];
#pragma unroll
      for (int reg = 0; reg < 4; reg++) acc[mi][nj][reg] = (float)m2.h[reg];
    }
  }

  int r0 = 2 * w * 16 + n, r1 = r0 + 16;
  h8 afA[2][4], afB[2][4];   // 2-deep named buffers (R20-proven, no spill)

#define LOADA(dst, l)                                                                \
  {                                                                                  \
    const _Float16* Ag = Abase + (size_t)(l) * 16384;                                \
    _Pragma("unroll")                                                                \
    for (int mi = 0; mi < 2; mi++)                                                   \
      _Pragma("unroll")                                                              \
      for (int kb = 0; kb < 4; kb++)                                                 \
        dst[mi][kb] = *(const h8*)(Ag + ((2 * w + mi) * 16 + n) * 128 + kb * 32 + q * 8); \
  }

#define STEPQ(af, l)                                                                 \
  {                                                                                  \
    int cu_ = ((l) - 1) & 1;                                                         \
    const _Float16* Dr = Dt + cu_ * DTS;                                             \
    _Float16* Dw = Dt + (cu_ ^ 1) * DTS;                                             \
    const float* vr = v32 + cu_ * 128;                                               \
    float* vw = v32 + (cu_ ^ 1) * 128;                                               \
    _Pragma("unroll")                                                                \
    for (int nj = 0; nj < 8; nj++) {                                                 \
      h8 bfr[4];                                                                     \
      _Pragma("unroll")                                                              \
      for (int kb = 0; kb < 4; kb++)                                                 \
        bfr[kb] = *(const h8*)&Dr[(nj * 16 + n) * 136 + kb * 32 + q * 8];            \
      _Pragma("unroll")                                                              \
      for (int mi = 0; mi < 2; mi++) {                                               \
        _Pragma("unroll")                                                            \
        for (int kb = 0; kb < 4; kb++)                                               \
          acc[mi][nj] = __builtin_amdgcn_mfma_f32_16x16x32_f16(af[mi][kb], bfr[kb], acc[mi][nj], 0, 0, 0); \
        acc[mi][nj] = __builtin_amdgcn_mfma_f32_16x16x32_f16(                        \
            af[mi][nj >> 1], (nj & 1) ? idO : idE, acc[mi][nj], 0, 0, 0);            \
      }                                                                              \
    }                                                                                \
    float dv0 = 0.f, dv1 = 0.f;                                                      \
    _Pragma("unroll")                                                                \
    for (int kb = 0; kb < 4; kb++) {                                                 \
      float4 p0 = *(const float4*)&vr[kb * 32 + q * 8];                              \
      float4 p1 = *(const float4*)&vr[kb * 32 + q * 8 + 4];                          \
      float vk[8] = {p0.x, p0.y, p0.z, p0.w, p1.x, p1.y, p1.z, p1.w};                \
      _Pragma("unroll")                                                              \
      for (int jj = 0; jj < 8; jj++) {                                               \
        dv0 += (float)af[0][kb][jj] * vk[jj];                                        \
        dv1 += (float)af[1][kb][jj] * vk[jj];                                        \
      }                                                                              \
    }                                                                                \
    dv0 += __shfl_xor(dv0, 16); dv0 += __shfl_xor(dv0, 32);                          \
    dv1 += __shfl_xor(dv1, 16); dv1 += __shfl_xor(dv1, 32);                          \
    float vold0 = vr[r0], vold1 = vr[r1];                                            \
    float bs0 = 0.f, bs1 = 0.f;                                                      \
    if (q == 0) {                                                                    \
      bs0 = Bs[(btb + (l)) * 128 + r0];                                              \
      bs1 = Bs[(btb + (l)) * 128 + r1];                                              \
    }                                                                                \
    _Pragma("unroll")                                                                \
    for (int mi = 0; mi < 2; mi++) {                                                 \
      int row0 = (2 * w + mi) * 16 + q * 4;                                          \
      _Pragma("unroll")                                                              \
      for (int nj = 0; nj < 8; nj++) {                                               \
        int col = nj * 16 + n;                                                       \
        union { _Float16 h[4]; uint2 u; } pk;                                        \
        _Pragma("unroll")                                                            \
        for (int reg = 0; reg < 4; reg++) pk.h[reg] = (_Float16)acc[mi][nj][reg];    \
        *(uint2*)&Dw[col * 136 + row0] = pk.u;                                       \
      }                                                                              \
    }                                                                                \
    if (q == 0) {                                                                    \
      vw[r0] = vold0 + dv0 + bs0;                                                    \
      vw[r1] = vold1 + dv1 + bs1;                                                    \
    }                                                                                \
    __syncthreads();                                                                 \
  }

  LOADA(afA, 1);
  for (int l = 1; l < nsteps; l += 2) {
    if (l + 1 < nsteps) LOADA(afB, l + 1);
    STEPQ(afA, l);
    if (l + 2 < nsteps) LOADA(afA, l + 2);
    if (l + 1 < nsteps) STEPQ(afB, l + 1);
  }
#undef LOADA
#undef STEPQ

  // tail: acc -> Dt buffer 0 (all waves past last step barrier -> safe)
#pragma unroll
  for (int mi = 0; mi < 2; mi++) {
    int row0 = (2 * w + mi) * 16 + q * 4;
#pragma unroll
    for (int nj = 0; nj < 8; nj++) {
      int col = nj * 16 + n;
#pragma unroll
      for (int reg = 0; reg < 4; reg++)
        Dt[(row0 + reg) * 136 + col] = (_Float16)acc[mi][nj][reg];
    }
  }
  __syncthreads();
  _Float16* og = Mr + (size_t)chunk * 16384;
#pragma unroll
  for (int it = 0; it < 8; it++) {
    int idx = tid + it * 256;
    int rowl = idx >> 4, ch = idx & 15;
    uint4 val = *(const uint4*)&Dt[rowl * 136 + ch * 8];
    *(uint4*)(og + rowl * 128 + ch * 8) = val;
  }
  if (tid < 128) vch[(size_t)chunk * 128 + tid] = v32[((nsteps - 1) & 1) * 128 + tid];
}

// ---------------- comp4 body (R22: double-buffer, one barrier/step) -------
__device__ __forceinline__ void comp4_body(const _Float16* __restrict__ in_map,
                                           const float* __restrict__ in_v,
                                           _Float16* __restrict__ out_map,
                                           float* __restrict__ out_v,
                                           int outIdx, int tid,
                                           _Float16* Dt, float* v32) {
  int w = tid >> 6, lane = tid & 63;
  int n = lane & 15, q = lane >> 4;
  size_t nbase = (size_t)outIdx * 4;

  const _Float16* P0 = in_map + nbase * 16384;
#pragma unroll
  for (int it = 0; it < 8; it++) {
    int idx = tid + it * 256;
    int rowl = idx & 127, c8 = (idx >> 7) * 8;
    uint4 pk = *(const uint4*)(P0 + rowl * 128 + c8);
    const _Float16* hp = (const _Float16*)&pk;
#pragma unroll
    for (int cx = 0; cx < 8; cx++) Dt[(c8 + cx) * 136 + rowl] = hp[cx];
  }
  if (tid < 128) v32[tid] = in_v[nbase * 128 + tid];
  h8 idE, idO;
#pragma unroll
  for (int jj = 0; jj < 8; jj++) {
    idE[jj] = (_Float16)((q * 8 + jj == n) ? 1.f : 0.f);
    idO[jj] = (_Float16)((q * 8 + jj == 16 + n) ? 1.f : 0.f);
  }
  __syncthreads();

  v4f acc[2][8];
#pragma unroll
  for (int mi = 0; mi < 2; mi++) {
    int row0 = (2 * w + mi) * 16 + q * 4;
#pragma unroll
    for (int nj = 0; nj < 8; nj++) {
      int col = nj * 16 + n;
      union { uint2 u; _Float16 h[4]; } m2;
      m2.u = *(const uint2*)&Dt[col * 136 + row0];
#pragma unroll
      for (int reg = 0; reg < 4; reg++) acc[mi][nj][reg] = (float)m2.h[reg];
    }
  }

  int r0 = 2 * w * 16 + n, r1 = r0 + 16;
  for (int j = 1; j < 4; j++) {
    int cu_ = (j - 1) & 1;
    const _Float16* Dr = Dt + cu_ * DTS;
    _Float16* Dw = Dt + (cu_ ^ 1) * DTS;
    const float* vr = v32 + cu_ * 128;
    float* vw = v32 + (cu_ ^ 1) * 128;
    const _Float16* Pj = in_map + (nbase + j) * 16384;
    h8 af[2][4];
#pragma unroll
    for (int mi = 0; mi < 2; mi++)
#pragma unroll
      for (int kb = 0; kb < 4; kb++)
        af[mi][kb] = *(const h8*)(Pj + ((2 * w + mi) * 16 + n) * 128 + kb * 32 + q * 8);
#pragma unroll
    for (int nj = 0; nj < 8; nj++) {
      h8 bfr[4];
#pragma unroll
      for (int kb = 0; kb < 4; kb++)
        bfr[kb] = *(const h8*)&Dr[(nj * 16 + n) * 136 + kb * 32 + q * 8];
#pragma unroll
      for (int mi = 0; mi < 2; mi++) {
#pragma unroll
        for (int kb = 0; kb < 4; kb++)
          acc[mi][nj] = __builtin_amdgcn_mfma_f32_16x16x32_f16(af[mi][kb], bfr[kb], acc[mi][nj], 0, 0, 0);
        acc[mi][nj] = __builtin_amdgcn_mfma_f32_16x16x32_f16(
            af[mi][nj >> 1], (nj & 1) ? idO : idE, acc[mi][nj], 0, 0, 0);
      }
    }
    float dv0 = 0.f, dv1 = 0.f;
#pragma unroll
    for (int kb = 0; kb < 4; kb++) {
      float4 p0 = *(const float4*)&vr[kb * 32 + q * 8];
      float4 p1 = *(const float4*)&vr[kb * 32 + q * 8 + 4];
      float vk[8] = {p0.x, p0.y, p0.z, p0.w, p1.x, p1.y, p1.z, p1.w};
#pragma unroll
      for (int jj = 0; jj < 8; jj++) {
        dv0 += (float)af[0][kb][jj] * vk[jj];
        dv1 += (float)af[1][kb][jj] * vk[jj];
      }
    }
    dv0 += __shfl_xor(dv0, 16); dv0 += __shfl_xor(dv0, 32);
    dv1 += __shfl_xor(dv1, 16); dv1 += __shfl_xor(dv1, 32);
    float vold0 = vr[r0], vold1 = vr[r1];
    float vj0 = 0.f, vj1 = 0.f;
    if (q == 0) {
      vj0 = in_v[(nbase + j) * 128 + r0];
      vj1 = in_v[(nbase + j) * 128 + r1];
    }
#pragma unroll
    for (int mi = 0; mi < 2; mi++) {
      int row0 = (2 * w + mi) * 16 + q * 4;
#pragma unroll
      for (int nj = 0; nj < 8; nj++) {
        int col = nj * 16 + n;
        union { _Float16 h[4]; uint2 u; } pk;
#pragma unroll
        for (int reg = 0; reg < 4; reg++) pk.h[reg] = (_Float16)acc[mi][nj][reg];
        *(uint2*)&Dw[col * 136 + row0] = pk.u;
      }
    }
    if (q == 0) {
      vw[r0] = vold0 + dv0 + vj0;
      vw[r1] = vold1 + dv1 + vj1;
    }
    __syncthreads();
  }
  // tail: final parity after j=3 is buffer 1; stage acc into buffer 0
#pragma unroll
  for (int mi = 0; mi < 2; mi++) {
    int row0 = (2 * w + mi) * 16 + q * 4;
#pragma unroll
    for (int nj = 0; nj < 8; nj++) {
      int col = nj * 16 + n;
#pragma unroll
      for (int reg = 0; reg < 4; reg++)
        Dt[(row0 + reg) * 136 + col] = (_Float16)acc[mi][nj][reg];
    }
  }
  __syncthreads();
  _Float16* og = out_map + (size_t)outIdx * 16384;
#pragma unroll
  for (int it = 0; it < 8; it++) {
    int idx = tid + it * 256;
    int rowl = idx >> 4, ch = idx & 15;
    uint4 val = *(const uint4*)&Dt[rowl * 136 + ch * 8];
    *(uint4*)(og + rowl * 128 + ch * 8) = val;
  }
  if (tid < 128) out_v[(size_t)outIdx * 128 + tid] = v32[128 + tid];
}

// ---------------- chainsuper body (R22: dbuf + shfl reduce) ---------------
__device__ __forceinline__ void chainsuper_body(const _Float16* __restrict__ Sr,
                                                const float* __restrict__ sv,
                                                float* __restrict__ yb,
                                                int c0, int scShift, int b, int tid,
                                                float* ybuf2) {
  int NS = 1 << (scShift - 2);
  int i = tid >> 1, hh = tid & 1;
  if (tid < 128) ybuf2[tid] = yb[(size_t)(b * NC + c0) * 128 + tid];
  __syncthreads();
  int cur = 0;

  uint4 arA[8], arB[8];
  float svA, svB;

#define LOADS(ar, svv, s)                                                            \
  {                                                                                  \
    const uint4* p = (const uint4*)(Sr + (size_t)(b * NS + (s)) * 16384 + i * 128 + hh * 64); \
    _Pragma("unroll")                                                                \
    for (int u = 0; u < 8; u++) ar[u] = p[u];                                        \
    svv = sv[(size_t)(b * NS + (s)) * 128 + i];                                      \
  }

#define STEPS(ar, svv, s)                                                            \
  {                                                                                  \
    const float* yr = ybuf2 + cur * 128;                                             \
    float* yw = ybuf2 + (cur ^ 1) * 128;                                             \
    float pt = 0.f;                                                                  \
    _Pragma("unroll")                                                                \
    for (int u = 0; u < 8; u++) {                                                    \
      union { uint4 v; _Float16 h[8]; } wv; wv.v = ar[u];                            \
      _Pragma("unroll")                                                              \
      for (int k = 0; k < 8; k++) pt += (float)wv.h[k] * yr[hh * 64 + u * 8 + k];    \
    }                                                                                \
    float ptO = __shfl_xor(pt, 1);                                                   \
    if (!hh) {                                                                       \
      float yn = yr[i] + pt;                                                         \
      yn = yn + ptO;                                                                 \
      yn = yn + svv;                                                                 \
      int cg = c0 + 4 * ((s) + 1);                                                   \
      if (cg < NC) yb[(size_t)(b * NC + cg) * 128 + i] = yn;                         \
      yw[i] = yn;                                                                    \
    }                                                                                \
    cur ^= 1;                                                                        \
    __syncthreads();                                                                 \
  }

  LOADS(arA, svA, 0);
  int s = 0;
  for (; s + 1 < NS; s += 2) {
    LOADS(arB, svB, s + 1);
    STEPS(arA, svA, s);
    if (s + 2 < NS) LOADS(arA, svA, s + 2);
    STEPS(arB, svB, s + 1);
  }
  if (s < NS) STEPS(arA, svA, s);
#undef LOADS
#undef STEPS
}

// ---------------- standalone stage kernels ----------------
__global__ __launch_bounds__(256) void k_chunkmap(const _Float16* __restrict__ A_sl,
                                                  const float* __restrict__ Bs,
                                                  _Float16* __restrict__ Mr,
                                                  float* __restrict__ vch,
                                                  int c0, int scShift) {
  __shared__ _Float16 Dt[2 * DTS];      // 69.6 KB (double buffer)
  __shared__ float v32[2 * 128];
  chunkmap_body(A_sl, Bs, Mr, vch, c0, scShift, blockIdx.x, threadIdx.x, Dt, v32);
}

__global__ __launch_bounds__(256) void k_comp4(const _Float16* __restrict__ in_map,
                                               const float* __restrict__ in_v,
                                               _Float16* __restrict__ out_map,
                                               float* __restrict__ out_v) {
  __shared__ _Float16 Dt[2 * DTS];
  __shared__ float v32[2 * 128];
  comp4_body(in_map, in_v, out_map, out_v, blockIdx.x, threadIdx.x, Dt, v32);
}

__global__ __launch_bounds__(256) void k_chainsuper(const _Float16* __restrict__ Sr,
                                                    const float* __restrict__ sv,
                                                    float* __restrict__ yb,
                                                    int c0, int scShift) {
  __shared__ float ybuf2[2 * 128];
  chainsuper_body(Sr, sv, yb, c0, scShift, blockIdx.x, threadIdx.x, ybuf2);
}

// ---------------- k_emit (R24): 512 threads, 4 lanes/row, 3-deep ----------
// Row i handled by 4 lanes (qd = tid&3), each a dot-32 over cols qd*32..+32.
// Reduce: pt += shfl_xor(pt,1); pt += shfl_xor(pt,2); qd==0 writes.
// 16 waves/CU (2 blocks x 8 waves); buffers are 4x uint4 (16 VGPR) each ->
// 3-deep rotation + hoisted steps 0-2 + prefix-j0 fit without spill.
__global__ __launch_bounds__(512, 4) void k_emit(const _Float16* __restrict__ A_sl,
                                                 const float* __restrict__ Bs,
                                                 const _Float16* __restrict__ Mr,
                                                 const float* __restrict__ vch,
                                                 const float* __restrict__ yb,
                                                 float* __restrict__ out,
                                                 int c0, int scShift) {
  __shared__ float ybuf2[2 * 128];
  int tid = threadIdx.x;
  int SC = 1 << scShift;
  int b = blockIdx.x >> scShift;
  int cc = blockIdx.x & (SC - 1);
  int c = c0 + cc;
  int i = tid >> 2, qd = tid & 3;
  int kpre = cc & 3;
  int cbase = c - kpre;
  size_t node0 = ((size_t)b << scShift) + (cc & ~3);
  int nst = min(L_, T_ - c * L_);       // 7 or 8 (>=7 always)
  size_t sidx0 = (size_t)blockIdx.x * L_;
  size_t btb = (size_t)b * T_ + c * L_;

  uint4 arA[4], arB[4], arC[4], arP[4];
  float bsA, bsB, bsC, vvP = 0.f;

#define LOADR(ar, bsv, l)                                                            \
  {                                                                                  \
    const uint4* p = (const uint4*)(A_sl + (sidx0 + (l)) * 16384 + i * 128 + qd * 32); \
    _Pragma("unroll")                                                                \
    for (int u = 0; u < 4; u++) ar[u] = p[u];                                        \
    bsv = Bs[(btb + (l)) * 128 + i];                                                 \
  }

  // hoisted: steps 0..2 + prefix j=0 in flight under ybuf load + prefix
  LOADR(arA, bsA, 0);
  LOADR(arB, bsB, 1);
  LOADR(arC, bsC, 2);
  if (kpre > 0) {
    const uint4* p2 = (const uint4*)(Mr + node0 * 16384 + i * 128 + qd * 32);
#pragma unroll
    for (int u = 0; u < 4; u++) arP[u] = p2[u];
    vvP = vch[node0 * 128 + i];
  }

  if (tid < 128) ybuf2[tid] = yb[(size_t)(b * NC + cbase) * 128 + tid];
  __syncthreads();
  int cur = 0;

  // prefix: apply kpre chunk maps
  for (int j = 0; j < kpre; j++) {
    uint4 ar[4];
    float vv;
    if (j == 0) {
#pragma unroll
      for (int u = 0; u < 4; u++) ar[u] = arP[u];
      vv = vvP;
    } else {
      const uint4* p = (const uint4*)(Mr + (node0 + j) * 16384 + i * 128 + qd * 32);
#pragma unroll
      for (int u = 0; u < 4; u++) ar[u] = p[u];
      vv = vch[(node0 + j) * 128 + i];
    }
    const float* yr = ybuf2 + cur * 128;
    float* yw = ybuf2 + (cur ^ 1) * 128;
    float pt = 0.f;
#pragma unroll
    for (int u = 0; u < 4; u++) {
      union { uint4 v; _Float16 h[8]; } wv; wv.v = ar[u];
#pragma unroll
      for (int k = 0; k < 8; k++) pt += (float)wv.h[k] * yr[qd * 32 + u * 8 + k];
    }
    pt += __shfl_xor(pt, 1);
    pt += __shfl_xor(pt, 2);
    if (qd == 0) {
      float yn = yr[i] + pt;
      yn = yn + vv;
      yw[i] = yn;
    }
    cur ^= 1;
    __syncthreads();
  }

#define STEPE(ar, bsv, l)                                                            \
  {                                                                                  \
    const float* yr = ybuf2 + cur * 128;                                             \
    float* yw = ybuf2 + (cur ^ 1) * 128;                                             \
    float pt = 0.f;                                                                  \
    _Pragma("unroll")                                                                \
    for (int u = 0; u < 4; u++) {                                                    \
      union { uint4 v; _Float16 h[8]; } wv; wv.v = ar[u];                            \
      _Pragma("unroll")                                                              \
      for (int k = 0; k < 8; k++) pt += (float)wv.h[k] * yr[qd * 32 + u * 8 + k];    \
    }                                                                                \
    pt += __shfl_xor(pt, 1);                                                         \
    pt += __shfl_xor(pt, 2);                                                         \
    if (qd == 0) {                                                                   \
      float yn = yr[i] + pt;                                                         \
      yn = yn + bsv;                                                                 \
      out[((size_t)b * S_ + (size_t)(c * L_ + (l) + 1)) * 128 + i] = yn;             \
      yw[i] = yn;                                                                    \
    }                                                                                \
    cur ^= 1;                                                                        \
    __syncthreads();                                                                 \
  }

  // straight-line 3-deep rotation (nst >= 7 always; step 7 guarded)
  STEPE(arA, bsA, 0); LOADR(arA, bsA, 3);
  STEPE(arB, bsB, 1); LOADR(arB, bsB, 4);
  STEPE(arC, bsC, 2); LOADR(arC, bsC, 5);
  STEPE(arA, bsA, 3); LOADR(arA, bsA, 6);
  STEPE(arB, bsB, 4); if (7 < nst) LOADR(arB, bsB, 7);
  STEPE(arC, bsC, 5);
  STEPE(arA, bsA, 6);
  if (7 < nst) STEPE(arB, bsB, 7);
#undef LOADR
#undef STEPE
}

// ---------------- fallback: plain sequential ----------------
__global__ __launch_bounds__(256) void k_seq(const float* __restrict__ X,
                                             const float* __restrict__ Wa,
                                             const float* __restrict__ Wb,
                                             float* __restrict__ out) {
  int b = blockIdx.x, tid = threadIdx.x;
  int i = tid >> 1, hh = tid & 1;
  __shared__ float y[H_], red[H_], xs[D_], bts[H_];
  if (tid < H_) y[tid] = out[(size_t)b * S_ * H_ + tid];
  __syncthreads();
  for (int t = 1; t < S_; t++) {
    if (tid < D_) xs[tid] = X[((size_t)b * S_ + t) * D_ + tid] * DTC;
    __syncthreads();
    if (tid < H_) {
      const float* wr = Wb + tid * KD;
      float acc = wr[0] * DTC;
#pragma unroll 8
      for (int d = 0; d < D_; d++) acc += xs[d] * wr[1 + d];
      bts[tid] = acc;
    }
    float part = 0.f;
    const float* yhalf = &y[hh * 64];
    for (int j = 0; j < 64; j++) {
      const float* wr = Wa + ((size_t)(i * H_) + hh * 64 + j) * KD;
      float a = wr[0] * DTC;
#pragma unroll 8
      for (int d = 0; d < D_; d++) a += xs[d] * wr[1 + d];
      part += a * yhalf[j];
    }
    if (hh) red[i] = part;
    __syncthreads();
    if (!hh) {
      float yn = y[i] + part + red[i] + bts[i];
      out[((size_t)b * S_ + t) * H_ + i] = yn;
      y[i] = yn;
    }
    __syncthreads();
  }
}

__global__ __launch_bounds__(128) void k_y0f(const float* __restrict__ X,
                                             const float* __restrict__ Wi,
                                             const float* __restrict__ bi,
                                             float* __restrict__ out) {
  int b = blockIdx.x, h = threadIdx.x;
  __shared__ float xs[D_];
  if (h < D_) xs[h] = X[(size_t)b * S_ * D_ + h];
  __syncthreads();
  float acc = bi[h];
  const float* wr = Wi + h * D_;
#pragma unroll 8
  for (int d = 0; d < D_; d++) acc += xs[d] * wr[d];
  out[(size_t)b * S_ * H_ + h] = acc;
}

extern "C" void kernel_launch(void* const* d_in, const int* in_sizes, int n_in,
                              void* d_out, int out_size, void* d_ws, size_t ws_size,
                              hipStream_t stream) {
  (void)in_sizes; (void)n_in; (void)out_size;
  const float* X  = (const float*)d_in[0];
  const float* Wi = (const float*)d_in[1];
  const float* bi = (const float*)d_in[2];
  const float* Wa = (const float*)d_in[3];
  const float* Wb = (const float*)d_in[4];
  float* out = (float*)d_out;
  char* ws = (char*)d_ws;

  size_t off = 0;
  auto alloc = [&](size_t bytes) { size_t o = off; off = (off + bytes + 255) & ~(size_t)255; return o; };
  size_t oBs  = alloc((size_t)B_ * T_ * 128 * 4);       //  8.38 MB
  size_t oYb  = alloc((size_t)B_ * NC * 128 * 4);       //  1.05 MB
  size_t oWaB = alloc((size_t)64 * 16384 * 2);          //  2.10 MB
  size_t oWa0 = alloc((size_t)16384 * 4);
  size_t oXs  = alloc((size_t)B_ * T_ * 64 * 2);        //  2.10 MB
  size_t fixed = off;

  const size_t APC  = (size_t)B_ * L_ * 16384 * 2;      // 2.10 MB
  const size_t MRPC = (size_t)B_ * 16384 * 2;           // 0.26 MB
  const size_t VCPC = (size_t)B_ * 128 * 4;             // 4 KB
  const size_t SRPC = (size_t)B_ * 16384 * 2 / 4;       // 64 KB
  const size_t SVPC = (size_t)B_ * 128;
  const size_t PER_SC = APC + MRPC + VCPC + SRPC + SVPC + 5 * 256;

  int SC = 0;
  if (ws_size > fixed) {
    size_t avail = ws_size - fixed;
    SC = 64;                             // ws=256MiB: SC=128 can never fit
    while (SC >= 4 && (size_t)SC * PER_SC > avail) SC >>= 1;
    if (SC < 4) SC = 0;
  }
  if (SC < 4) {
    k_y0f<<<B_, 128, 0, stream>>>(X, Wi, bi, out);
    k_seq<<<B_, 256, 0, stream>>>(X, Wa, Wb, out);
    return;
  }
  int scShift = __builtin_ctz(SC);

  size_t oMr = alloc((size_t)SC * MRPC);
  size_t oVc = alloc((size_t)SC * VCPC);
  size_t oSr = alloc((size_t)SC * SRPC);
  size_t oSv = alloc((size_t)SC * SVPC);
  size_t oA  = alloc((size_t)SC * APC);

  float*    Bs    = (float*)(ws + oBs);
  float*    yb    = (float*)(ws + oYb);
  _Float16* Wa16B = (_Float16*)(ws + oWaB);
  float*    Wa0   = (float*)(ws + oWa0);
  _Float16* Xs16  = (_Float16*)(ws + oXs);
  _Float16* Mr    = (_Float16*)(ws + oMr);
  float*    vch   = (float*)(ws + oVc);
  _Float16* Sr    = (_Float16*)(ws + oSr);
  float*    sv    = (float*)(ws + oSv);
  _Float16* A_sl  = (_Float16*)(ws + oA);

  // merged prep: Wa swizzle + Xs16 + Bs + y0 in one dispatch
  k_prep<<<9222, 256, 0, stream>>>(Wa, Wa16B, Wa0, X, Xs16, Wb, Bs, Wi, bi, out, yb);

  int nslices = NC / SC;
  int chunks = B_ * SC;
  int amat_gx = (B_ * SC * L_) / 32;
  for (int si = 0; si < nslices; si++) {
    int c0 = si * SC;
    k_amat<<<dim3(amat_gx, 32), 256, 0, stream>>>(Xs16, Wa16B, Wa0, A_sl, c0, scShift);
    k_chunkmap<<<chunks, 256, 0, stream>>>(A_sl, Bs, Mr, vch, c0, scShift);
    k_comp4<<<chunks / 4, 256, 0, stream>>>(Mr, vch, Sr, sv);
    k_chainsuper<<<B_, 256, 0, stream>>>(Sr, sv, yb, c0, scShift);
    k_emit<<<chunks, 512, 0, stream>>>(A_sl, Bs, Mr, vch, yb, out, c0, scShift);
  }
}